// Round 2
// baseline (5838.144 us; speedup 1.0000x reference)
//
#include <hip/hip_runtime.h>
#include <cstddef>
#include <cstdint>

// ---------------- problem constants ----------------
#define B_SZ    2
#define SEQ     2048
#define DMODEL  2048
#define DINNER  4096
#define DSTATE  128
#define NHEADS  64
#define HEADDIM 64
#define DXBC    4352          // DINNER + 2*DSTATE
#define NPROJ   8448          // DINNER + DXBC (z | xBC); dt handled separately in fp32
#define CHUNK   64
#define NCHUNK  32
#define TOKENS  (B_SZ*SEQ)    // 4096

// ---- bf16 <-> f32 helpers (raw ushort storage, RNE) ----
__device__ inline float us2f(unsigned short u) {
  union { uint32_t i; float f; } c; c.i = ((uint32_t)u) << 16; return c.f;
}
__device__ inline unsigned short f2us(float f) {
  union { float f; uint32_t i; } c; c.f = f;
  uint32_t r = (c.i + 0x7fffu + ((c.i >> 16) & 1u)) >> 16;
  return (unsigned short)r;
}
__device__ inline float plo(uint32_t v) {  // low bf16 of a packed pair
  union { uint32_t i; float f; } c; c.i = v << 16; return c.f;
}
__device__ inline float phi(uint32_t v) {  // high bf16
  union { uint32_t i; float f; } c; c.i = v & 0xffff0000u; return c.f;
}

// ws layout:
//   proj (bf16) : TOKENS*NPROJ  ushort = 69.2 MB   [z cols 0..4095 | xBC cols 4096..8447]
//   dtr  (f32)  : TOKENS*NHEADS float  =  1.0 MB
//   yscan(bf16) : TOKENS*DINNER ushort = 33.6 MB   (Y, then y_normed in place)
// total ~103.8 MB  (round-0 used 413 MB -> suspected d_ws overflow fault)

// ---------------- tiled NT GEMM: C[M,N] = A[M,K] @ B[N,K]^T ----------------
// A: float or bf16(ushort); B: float; C: float or bf16. 128x128 tile, BK=16.
__device__ inline void loadA4(const float* p, float* d) {
  float4 v = *(const float4*)p; d[0]=v.x; d[1]=v.y; d[2]=v.z; d[3]=v.w;
}
__device__ inline void loadA4(const unsigned short* p, float* d) {
  ushort4 v = *(const ushort4*)p;
  d[0]=us2f(v.x); d[1]=us2f(v.y); d[2]=us2f(v.z); d[3]=us2f(v.w);
}
__device__ inline void store8(float* C, size_t off, const float* v) {
  *(float4*)(C + off)     = make_float4(v[0], v[1], v[2], v[3]);
  *(float4*)(C + off + 4) = make_float4(v[4], v[5], v[6], v[7]);
}
__device__ inline void store8(unsigned short* C, size_t off, const float* v) {
  ushort4 a; a.x=f2us(v[0]); a.y=f2us(v[1]); a.z=f2us(v[2]); a.w=f2us(v[3]);
  ushort4 b; b.x=f2us(v[4]); b.y=f2us(v[5]); b.z=f2us(v[6]); b.w=f2us(v[7]);
  *(ushort4*)(C + off) = a; *(ushort4*)(C + off + 4) = b;
}

template<typename AT, typename OT>
__global__ __launch_bounds__(256) void gemm_nt(
    const AT* __restrict__ A, const float* __restrict__ Bw,
    OT* __restrict__ C, int M, int N, int K) {
  __shared__ float As[16][128+4];
  __shared__ float Bs[16][128+4];
  const int bm = blockIdx.y * 128;
  const int bn = blockIdx.x * 128;
  const int tid = threadIdx.x;
  const int tx = tid & 15, ty = tid >> 4;

  float acc[8][8];
  #pragma unroll
  for (int i = 0; i < 8; ++i)
    #pragma unroll
    for (int j = 0; j < 8; ++j) acc[i][j] = 0.f;

  for (int k0 = 0; k0 < K; k0 += 16) {
    #pragma unroll
    for (int r = 0; r < 2; ++r) {
      int i = tid + r * 256;          // 0..511
      int m  = i >> 2;                // 0..127
      int kv = (i & 3) << 2;          // 0,4,8,12
      float va[4];
      loadA4(A + (size_t)(bm + m) * K + k0 + kv, va);
      As[kv+0][m] = va[0]; As[kv+1][m] = va[1]; As[kv+2][m] = va[2]; As[kv+3][m] = va[3];
      float vb[4] = {0.f, 0.f, 0.f, 0.f};
      if (bn + m < N) loadA4(Bw + (size_t)(bn + m) * K + k0 + kv, vb);
      Bs[kv+0][m] = vb[0]; Bs[kv+1][m] = vb[1]; Bs[kv+2][m] = vb[2]; Bs[kv+3][m] = vb[3];
    }
    __syncthreads();
    #pragma unroll
    for (int kk = 0; kk < 16; ++kk) {
      float ra[8], rb[8];
      *(float4*)&ra[0] = *(const float4*)&As[kk][ty*8];
      *(float4*)&ra[4] = *(const float4*)&As[kk][ty*8+4];
      *(float4*)&rb[0] = *(const float4*)&Bs[kk][tx*8];
      *(float4*)&rb[4] = *(const float4*)&Bs[kk][tx*8+4];
      #pragma unroll
      for (int i = 0; i < 8; ++i)
        #pragma unroll
        for (int j = 0; j < 8; ++j) acc[i][j] += ra[i] * rb[j];
    }
    __syncthreads();
  }
  #pragma unroll
  for (int i = 0; i < 8; ++i) {
    int m  = bm + ty*8 + i;
    int n0 = bn + tx*8;
    if (n0 < N) store8(C, (size_t)m * N + n0, &acc[i][0]);
  }
}

// ---------------- dt GEMV (fp32): dtr[t,h] = x[t,:] . W[8448+h,:] ----------------
__global__ __launch_bounds__(256) void dt_gemv(
    const float* __restrict__ x, const float* __restrict__ W,
    float* __restrict__ dtr) {
  const int t = blockIdx.x;
  const int tid = threadIdx.x;
  __shared__ float xrow[DMODEL];
  for (int i = tid; i < DMODEL; i += 256) xrow[i] = x[(size_t)t * DMODEL + i];
  __syncthreads();
  const int h = tid >> 2, q = tid & 3;
  const float4* wp = (const float4*)(W + (size_t)(NPROJ + h) * DMODEL + q * 512);
  const float4* xp = (const float4*)(xrow + q * 512);
  float acc = 0.f;
  #pragma unroll 4
  for (int u = 0; u < 128; ++u) {
    float4 a = xp[u], b = wp[u];
    acc += a.x*b.x + a.y*b.y + a.z*b.z + a.w*b.w;
  }
  acc += __shfl_xor(acc, 1, 64);
  acc += __shfl_xor(acc, 2, 64);
  if (q == 0) dtr[(size_t)t * NHEADS + h] = acc;
}

// ---------------- fused SSD scan: one block per (b,h), 512 threads ----------------
// Recomputes conv+SiLU on the fly from proj (bf16). Running state in registers.
// Reference quirk preserved: Y_off uses POST-chunk state S_c = exp(Alast_c)*S_{c-1} + cs_c.
__global__ __launch_bounds__(512) void ssd_fused(
    const unsigned short* __restrict__ proj, const float* __restrict__ dtr,
    const float* __restrict__ cw, const float* __restrict__ cb,
    const float* __restrict__ A_log, const float* __restrict__ dt_bias,
    unsigned short* __restrict__ yscan) {
  const int h = blockIdx.x & 63;
  const int b = blockIdx.x >> 6;
  const int tid = threadIdx.x;

  __shared__ unsigned short sB[64*130];   // B tile; reused as S (bf16) after state update
  __shared__ unsigned short sC[64*130];   // C tile
  __shared__ unsigned short sX[64*66];    // X = silu(conv(x)) * dt
  __shared__ float sW[64*65];             // masked decay*G matrix
  __shared__ float sdt[64], sAc[64], sdecay[64], seAc[64];

  const float Ah = -expf(A_log[h]);
  const float dbias = dt_bias[h];

  float S[16];
  #pragma unroll
  for (int j = 0; j < 16; ++j) S[j] = 0.f;

  const int lG  = tid >> 3;   // 0..63 (G-row / state p / stage mappings)
  const int oc  = tid & 7;    // 0..7

  for (int c = 0; c < NCHUNK; ++c) {
    const int t0 = b * SEQ + c * CHUNK;     // global token of chunk start
    __syncthreads();                         // LDS reuse guard from previous chunk

    // (a) dt
    if (tid < 64) {
      float raw = dtr[(size_t)(t0 + tid) * NHEADS + h] + dbias;
      sdt[tid] = (raw > 20.f) ? raw : log1pf(expf(raw));
    }
    // (b) B,C staging with on-the-fly conv+silu: xBC channels 4096..4351
    for (int i = tid; i < 64*256; i += 512) {
      int s = i >> 8, ch = i & 255;
      int cx = 4096 + ch;                    // xBC channel
      int lb = c * CHUNK + s;                // batch-local position
      float acc = cb[cx];
      #pragma unroll
      for (int j = 0; j < 4; ++j) {
        int ll = lb - 3 + j;
        if (ll >= 0)
          acc += cw[cx*4 + j] * us2f(proj[(size_t)(b*SEQ + ll) * NPROJ + DINNER + cx]);
      }
      float v = acc / (1.f + expf(-acc));
      if (ch < 128) sB[s*130 + ch] = f2us(v);
      else          sC[s*130 + (ch - 128)] = f2us(v);
    }
    __syncthreads();
    // (c) serial cumsum of dt*Ah
    if (tid == 0) {
      float run = 0.f;
      for (int s = 0; s < CHUNK; ++s) { run += sdt[s] * Ah; sAc[s] = run; }
    }
    __syncthreads();
    // (d) decay / exp(Ac)
    if (tid < 64) {
      float last = sAc[63];
      sdecay[tid] = expf(last - sAc[tid]);
      seAc[tid]   = expf(sAc[tid]);
    }
    // (e) X staging (needs dt): x_ssm channels h*64..h*64+63
    for (int i = tid; i < 64*64; i += 512) {
      int s = i >> 6, p = i & 63;
      int cx = h * HEADDIM + p;
      int lb = c * CHUNK + s;
      float acc = cb[cx];
      #pragma unroll
      for (int j = 0; j < 4; ++j) {
        int ll = lb - 3 + j;
        if (ll >= 0)
          acc += cw[cx*4 + j] * us2f(proj[(size_t)(b*SEQ + ll) * NPROJ + DINNER + cx]);
      }
      float v = acc / (1.f + expf(-acc));
      sX[s*66 + p] = f2us(v * sdt[s]);
    }
    __syncthreads();

    // (f) G[l, s-strip]: g[j] = sum_n C[l,n]*B[s=oc*8+j, n]
    float g[8];
    #pragma unroll
    for (int j = 0; j < 8; ++j) g[j] = 0.f;
    {
      const uint32_t* Cu = (const uint32_t*)&sC[lG * 130];
      const uint32_t* Bu[8];
      #pragma unroll
      for (int j = 0; j < 8; ++j) Bu[j] = (const uint32_t*)&sB[(oc*8 + j) * 130];
      for (int u = 0; u < 64; ++u) {
        uint32_t cv = Cu[u];
        float c0 = plo(cv), c1 = phi(cv);
        #pragma unroll
        for (int j = 0; j < 8; ++j) {
          uint32_t bv = Bu[j][u];
          g[j] += c0 * plo(bv) + c1 * phi(bv);
        }
      }
    }
    // (g) masked decay weights: W[l,s] = (s<=l) ? g * exp(Ac[l]-Ac[s]) : 0
    {
      float acl = sAc[lG];
      #pragma unroll
      for (int j = 0; j < 8; ++j) {
        int s = oc*8 + j;
        sW[lG*65 + s] = (s <= lG) ? g[j] * expf(acl - sAc[s]) : 0.f;
      }
    }
    // (h) state update: S[p, n] = S*exp(Alast) + sum_s B[s,n]*decay[s]*X[s,p]
    {
      float elast = expf(sAc[63]);
      #pragma unroll
      for (int j = 0; j < 16; ++j) S[j] *= elast;
      for (int s = 0; s < CHUNK; ++s) {
        float w = sdecay[s] * us2f(sX[s*66 + lG]);     // p = lG
        const uint32_t* Bu = (const uint32_t*)&sB[s*130 + oc*16];
        #pragma unroll
        for (int ju = 0; ju < 8; ++ju) {
          uint32_t bv = Bu[ju];
          S[2*ju]   += plo(bv) * w;
          S[2*ju+1] += phi(bv) * w;
        }
      }
    }
    __syncthreads();
    // (i) dump S (post-chunk) as bf16 into sB region: Ssm[p][n]
    #pragma unroll
    for (int j = 0; j < 16; ++j) sB[lG*130 + oc*16 + j] = f2us(S[j]);
    __syncthreads();
    // (j) outputs: y[l,p] = Ydiag + Yoff*exp(Ac[l])
    for (int o = tid; o < CHUNK*HEADDIM; o += 512) {
      int l = o >> 6, p = o & 63;
      float yd = 0.f;
      for (int s = 0; s <= l; ++s)
        yd += sW[l*65 + s] * us2f(sX[s*66 + p]);
      float yo = 0.f;
      const uint32_t* Cu = (const uint32_t*)&sC[l * 130];
      const uint32_t* Su = (const uint32_t*)&sB[p * 130];
      for (int u = 0; u < 64; ++u) {
        uint32_t cv = Cu[u], sv = Su[u];
        yo += plo(cv) * plo(sv) + phi(cv) * phi(sv);
      }
      float y = yd + yo * seAc[l];
      yscan[(size_t)(t0 + l) * DINNER + h * HEADDIM + p] = f2us(y);
    }
  }
}

// ---------------- D-skip + gating + RMSNorm (in place on yscan) ----------------
__global__ __launch_bounds__(256) void gate_rmsnorm(
    const unsigned short* __restrict__ proj, const float* __restrict__ cw,
    const float* __restrict__ cb, const float* __restrict__ Dv,
    const float* __restrict__ norm_w, unsigned short* __restrict__ yscan) {
  const int t = blockIdx.x;
  const int tid = threadIdx.x;
  const int b = t >> 11, lb = t & 2047;
  __shared__ float ybuf[DINNER];   // 16 KB
  __shared__ float wpart[4];
  __shared__ float sinv;
  float ss = 0.f;
  for (int i = tid; i < DINNER; i += 256) {
    float zv = us2f(proj[(size_t)t * NPROJ + i]);
    // D-skip: recompute x_heads = silu(conv(xBC channel i))
    float acc = cb[i];
    #pragma unroll
    for (int j = 0; j < 4; ++j) {
      int ll = lb - 3 + j;
      if (ll >= 0)
        acc += cw[i*4 + j] * us2f(proj[(size_t)(b*SEQ + ll) * NPROJ + DINNER + i]);
    }
    float xh = acc / (1.f + expf(-acc));
    float yv = us2f(yscan[(size_t)t * DINNER + i]) + xh * Dv[i >> 6];
    yv = yv * (zv / (1.f + expf(-zv)));
    ybuf[i] = yv;
    ss += yv * yv;
  }
  #pragma unroll
  for (int off = 32; off > 0; off >>= 1) ss += __shfl_down(ss, off, 64);
  if ((tid & 63) == 0) wpart[tid >> 6] = ss;
  __syncthreads();
  if (tid == 0) {
    float tot = wpart[0] + wpart[1] + wpart[2] + wpart[3];
    sinv = 1.f / sqrtf(tot / (float)DINNER + 1e-5f);
  }
  __syncthreads();
  float inv = sinv;
  for (int i = tid; i < DINNER; i += 256)
    yscan[(size_t)t * DINNER + i] = f2us(ybuf[i] * inv * norm_w[i]);
}

// ---------------- launch ----------------
extern "C" void kernel_launch(void* const* d_in, const int* in_sizes, int n_in,
                              void* d_out, int out_size, void* d_ws, size_t ws_size,
                              hipStream_t stream) {
  const float* x          = (const float*)d_in[0];
  const float* in_proj_w  = (const float*)d_in[1];
  const float* conv_w     = (const float*)d_in[2];
  const float* conv_b     = (const float*)d_in[3];
  const float* A_log      = (const float*)d_in[4];
  const float* Dv         = (const float*)d_in[5];
  const float* dt_bias    = (const float*)d_in[6];
  const float* norm_w     = (const float*)d_in[7];
  const float* out_proj_w = (const float*)d_in[8];
  float* out = (float*)d_out;

  // ws carve-up (bytes): proj(bf16) | dtr(f32) | yscan(bf16)
  unsigned short* proj  = (unsigned short*)d_ws;                       // TOKENS*NPROJ
  float*          dtr   = (float*)(proj + (size_t)TOKENS * NPROJ);     // TOKENS*NHEADS
  unsigned short* yscan = (unsigned short*)(dtr + (size_t)TOKENS * NHEADS);

  // 1) proj(z|xBC) = x @ in_proj_w[0:8448]^T   -> bf16
  {
    dim3 grid(NPROJ/128, TOKENS/128);   // 66 x 32
    gemm_nt<float, unsigned short><<<grid, 256, 0, stream>>>(
        x, in_proj_w, proj, TOKENS, NPROJ, DMODEL);
  }
  // 2) dt_raw = x @ in_proj_w[8448:8512]^T  -> fp32 (precision-critical path)
  dt_gemv<<<TOKENS, 256, 0, stream>>>(x, in_proj_w, dtr);
  // 3) fused SSD scan (conv+silu on the fly, state in registers)
  ssd_fused<<<B_SZ*NHEADS, 512, 0, stream>>>(proj, dtr, conv_w, conv_b,
                                             A_log, dt_bias, yscan);
  // 4) D-skip + gate + rmsnorm (in place)
  gate_rmsnorm<<<TOKENS, 256, 0, stream>>>(proj, conv_w, conv_b, Dv, norm_w, yscan);
  // 5) out = yn @ out_proj_w^T  (fp32 out)
  {
    dim3 grid(DMODEL/128, TOKENS/128);  // 16 x 32
    gemm_nt<unsigned short, float><<<grid, 256, 0, stream>>>(
        yscan, out_proj_w, out, TOKENS, DMODEL, DINNER);
  }
}

// Round 3
// 3928.072 us; speedup vs baseline: 1.4863x; 1.4863x over previous
//
#include <hip/hip_runtime.h>
#include <cstddef>
#include <cstdint>

// ---------------- problem constants ----------------
#define B_SZ    2
#define SEQ     2048
#define DMODEL  2048
#define DINNER  4096
#define DSTATE  128
#define NHEADS  64
#define HEADDIM 64
#define DXBC    4352          // DINNER + 2*DSTATE
#define NPROJ   8448          // DINNER + DXBC (z | xBC); dt handled separately in fp32
#define CHUNK   64
#define NCHUNK  32
#define TOKENS  (B_SZ*SEQ)    // 4096

// ---- bf16 <-> f32 helpers ----
__device__ inline float us2f(unsigned short u) {
  union { uint32_t i; float f; } c; c.i = ((uint32_t)u) << 16; return c.f;
}
__device__ inline unsigned short f2us(float f) {
  union { float f; uint32_t i; } c; c.f = f;
  uint32_t r = (c.i + 0x7fffu + ((c.i >> 16) & 1u)) >> 16;
  return (unsigned short)r;
}
__device__ inline float plo(uint32_t v) {
  union { uint32_t i; float f; } c; c.i = v << 16; return c.f;
}
__device__ inline float phi(uint32_t v) {
  union { uint32_t i; float f; } c; c.i = v & 0xffff0000u; return c.f;
}

// ---------------- tiled NT GEMM: C[M,N] = A[M,K] @ B[N,K]^T ----------------
__device__ inline void loadA4(const float* p, float* d) {
  float4 v = *(const float4*)p; d[0]=v.x; d[1]=v.y; d[2]=v.z; d[3]=v.w;
}
__device__ inline void loadA4(const unsigned short* p, float* d) {
  ushort4 v = *(const ushort4*)p;
  d[0]=us2f(v.x); d[1]=us2f(v.y); d[2]=us2f(v.z); d[3]=us2f(v.w);
}
__device__ inline void store8(float* C, size_t off, const float* v) {
  *(float4*)(C + off)     = make_float4(v[0], v[1], v[2], v[3]);
  *(float4*)(C + off + 4) = make_float4(v[4], v[5], v[6], v[7]);
}
__device__ inline void store8(unsigned short* C, size_t off, const float* v) {
  ushort4 a; a.x=f2us(v[0]); a.y=f2us(v[1]); a.z=f2us(v[2]); a.w=f2us(v[3]);
  ushort4 b; b.x=f2us(v[4]); b.y=f2us(v[5]); b.z=f2us(v[6]); b.w=f2us(v[7]);
  *(ushort4*)(C + off) = a; *(ushort4*)(C + off + 4) = b;
}

template<typename AT, typename OT>
__global__ __launch_bounds__(256) void gemm_nt(
    const AT* __restrict__ A, const float* __restrict__ Bw,
    OT* __restrict__ C, int M, int N, int K) {
  __shared__ float As[16][128+4];
  __shared__ float Bs[16][128+4];
  const int bm = blockIdx.y * 128;
  const int bn = blockIdx.x * 128;
  const int tid = threadIdx.x;
  const int tx = tid & 15, ty = tid >> 4;

  float acc[8][8];
  #pragma unroll
  for (int i = 0; i < 8; ++i)
    #pragma unroll
    for (int j = 0; j < 8; ++j) acc[i][j] = 0.f;

  for (int k0 = 0; k0 < K; k0 += 16) {
    #pragma unroll
    for (int r = 0; r < 2; ++r) {
      int i = tid + r * 256;
      int m  = i >> 2;
      int kv = (i & 3) << 2;
      float va[4];
      loadA4(A + (size_t)(bm + m) * K + k0 + kv, va);
      As[kv+0][m] = va[0]; As[kv+1][m] = va[1]; As[kv+2][m] = va[2]; As[kv+3][m] = va[3];
      float vb[4] = {0.f, 0.f, 0.f, 0.f};
      if (bn + m < N) loadA4(Bw + (size_t)(bn + m) * K + k0 + kv, vb);
      Bs[kv+0][m] = vb[0]; Bs[kv+1][m] = vb[1]; Bs[kv+2][m] = vb[2]; Bs[kv+3][m] = vb[3];
    }
    __syncthreads();
    #pragma unroll
    for (int kk = 0; kk < 16; ++kk) {
      float ra[8], rb[8];
      *(float4*)&ra[0] = *(const float4*)&As[kk][ty*8];
      *(float4*)&ra[4] = *(const float4*)&As[kk][ty*8+4];
      *(float4*)&rb[0] = *(const float4*)&Bs[kk][tx*8];
      *(float4*)&rb[4] = *(const float4*)&Bs[kk][tx*8+4];
      #pragma unroll
      for (int i = 0; i < 8; ++i)
        #pragma unroll
        for (int j = 0; j < 8; ++j) acc[i][j] += ra[i] * rb[j];
    }
    __syncthreads();
  }
  #pragma unroll
  for (int i = 0; i < 8; ++i) {
    int m  = bm + ty*8 + i;
    int n0 = bn + tx*8;
    if (n0 < N) store8(C, (size_t)m * N + n0, &acc[i][0]);
  }
}

// ---------------- dt GEMV (fp32) ----------------
__global__ __launch_bounds__(256) void dt_gemv(
    const float* __restrict__ x, const float* __restrict__ W,
    float* __restrict__ dtr) {
  const int t = blockIdx.x;
  const int tid = threadIdx.x;
  __shared__ float xrow[DMODEL];
  for (int i = tid; i < DMODEL; i += 256) xrow[i] = x[(size_t)t * DMODEL + i];
  __syncthreads();
  const int h = tid >> 2, q = tid & 3;
  const float4* wp = (const float4*)(W + (size_t)(NPROJ + h) * DMODEL + q * 512);
  const float4* xp = (const float4*)(xrow + q * 512);
  float acc = 0.f;
  #pragma unroll 4
  for (int u = 0; u < 128; ++u) {
    float4 a = xp[u], b = wp[u];
    acc += a.x*b.x + a.y*b.y + a.z*b.z + a.w*b.w;
  }
  acc += __shfl_xor(acc, 1, 64);
  acc += __shfl_xor(acc, 2, 64);
  if (q == 0) dtr[(size_t)t * NHEADS + h] = acc;
}

// ================= NEW split-scan path =================
// bcact layout: [token][256]  (B: ch 0..127, C: ch 128..255), bf16
// gbuf:  [(b*32+c)][64*64] f32, G[l][s] = sum_n C[l,n]*B[s,n]  (head-independent)
// cs:    [((b*64+h)*32+c)][p*128+n] bf16 (chunk states -> scanned states in place)
// acs:   [((b*64+h)*32+c)][l] f32 chunk-local A-cumsum

// ---- A1: conv+silu B,C once per (b,c); G = C.B^T shared by all heads ----
__global__ __launch_bounds__(256) void bc_conv_g(
    const unsigned short* __restrict__ proj, const float* __restrict__ cw,
    const float* __restrict__ cb, unsigned short* __restrict__ bcact,
    float* __restrict__ gbuf) {
  const int c = blockIdx.x & 31;
  const int b = blockIdx.x >> 5;
  const int tid = threadIdx.x;
  const int t0 = b * SEQ + c * CHUNK;
  __shared__ unsigned short sB[64*130];
  __shared__ unsigned short sC[64*130];
  for (int i = tid; i < 64*256; i += 256) {
    int s = i >> 8, ch = i & 255;
    int cx = 4096 + ch;                // xBC channel
    int lb = c * CHUNK + s;
    float acc = cb[cx];
    #pragma unroll
    for (int j = 0; j < 4; ++j) {
      int ll = lb - 3 + j;
      if (ll >= 0)
        acc += cw[cx*4 + j] * us2f(proj[(size_t)(b*SEQ + ll) * NPROJ + DINNER + cx]);
    }
    float v = acc / (1.f + expf(-acc));
    unsigned short uv = f2us(v);
    if (ch < 128) sB[s*130 + ch] = uv;
    else          sC[s*130 + (ch - 128)] = uv;
    bcact[(size_t)(t0 + s) * 256 + ch] = uv;
  }
  __syncthreads();
  const int l = tid >> 2, q = tid & 3;
  float g[16];
  #pragma unroll
  for (int j = 0; j < 16; ++j) g[j] = 0.f;
  const uint32_t* Cu = (const uint32_t*)&sC[l * 130];
  for (int u = 0; u < 64; ++u) {
    uint32_t cv = Cu[u];
    float c0 = plo(cv), c1 = phi(cv);
    #pragma unroll
    for (int j = 0; j < 16; ++j) {
      uint32_t bv = ((const uint32_t*)&sB[(q*16 + j) * 130])[u];
      g[j] += c0 * plo(bv) + c1 * phi(bv);
    }
  }
  float* gr = gbuf + ((size_t)(b*NCHUNK + c)) * 4096 + l*64 + q*16;
  #pragma unroll
  for (int j = 0; j < 16; ++j) gr[j] = g[j];
}

// ---- A2: per (b,c,h): dt/cumsum, X stage, Y_diag + D-skip, chunk state ----
__global__ __launch_bounds__(256) void ssd_phase_a2(
    const unsigned short* __restrict__ proj, const unsigned short* __restrict__ bcact,
    const float* __restrict__ dtr, const float* __restrict__ cw,
    const float* __restrict__ cb, const float* __restrict__ A_log,
    const float* __restrict__ dt_bias, const float* __restrict__ gbuf,
    const float* __restrict__ Dv,
    unsigned short* __restrict__ cs, float* __restrict__ acs,
    unsigned short* __restrict__ yscan) {
  const int h = blockIdx.x & 63;
  const int c = (blockIdx.x >> 6) & 31;
  const int b = blockIdx.x >> 11;
  const int tid = threadIdx.x;
  const int t0 = b * SEQ + c * CHUNK;

  __shared__ unsigned short sB[64*130];
  __shared__ unsigned short sX[64*66];
  __shared__ unsigned short sXh[64*66];
  __shared__ float sW[64*65];
  __shared__ float sdt[64], sAc[64], sdecay[64];

  const float Ah = -expf(A_log[h]);
  // dt + inclusive cumsum (wave 0 only, shuffle scan)
  if (tid < 64) {
    float raw = dtr[(size_t)(t0 + tid) * NHEADS + h] + dt_bias[h];
    float dt = (raw > 20.f) ? raw : log1pf(expf(raw));
    sdt[tid] = dt;
    float v = dt * Ah;
    #pragma unroll
    for (int off = 1; off < 64; off <<= 1) {
      float o = __shfl_up(v, off, 64);
      if (tid >= off) v += o;
    }
    sAc[tid] = v;
    acs[((size_t)((b*NHEADS + h)*NCHUNK + c))*64 + tid] = v;
  }
  // B tile from bcact
  for (int i = tid; i < 64*128; i += 256) {
    int s = i >> 7, n = i & 127;
    sB[s*130 + n] = bcact[(size_t)(t0 + s) * 256 + n];
  }
  __syncthreads();
  const float alast = sAc[63];
  if (tid < 64) sdecay[tid] = expf(alast - sAc[tid]);
  // X staging (conv recompute, head channels only)
  for (int i = tid; i < 64*64; i += 256) {
    int s = i >> 6, p = i & 63;
    int cx = h * HEADDIM + p;
    int lb = c * CHUNK + s;
    float acc = cb[cx];
    #pragma unroll
    for (int j = 0; j < 4; ++j) {
      int ll = lb - 3 + j;
      if (ll >= 0)
        acc += cw[cx*4 + j] * us2f(proj[(size_t)(b*SEQ + ll) * NPROJ + DINNER + cx]);
    }
    float xh = acc / (1.f + expf(-acc));
    sXh[s*66 + p] = f2us(xh);
    sX[s*66 + p]  = f2us(xh * sdt[s]);
  }
  // masked decay matrix from shared G
  {
    const float* gr = gbuf + ((size_t)(b*NCHUNK + c)) * 4096;
    for (int i = tid; i < 4096; i += 256) {
      int l = i >> 6, s = i & 63;
      sW[l*65 + s] = (s <= l) ? gr[i] * expf(sAc[l] - sAc[s]) : 0.f;
    }
  }
  __syncthreads();

  // Y_diag + D-skip
  const float Dh = Dv[h];
  for (int o = tid; o < CHUNK*HEADDIM; o += 256) {
    int l = o >> 6, p = o & 63;
    float yd = 0.f;
    for (int s = 0; s <= l; ++s) yd += sW[l*65 + s] * us2f(sX[s*66 + p]);
    yd += us2f(sXh[l*66 + p]) * Dh;
    yscan[(size_t)(t0 + l) * DINNER + h*HEADDIM + p] = f2us(yd);
  }
  // chunk state cs[p,n] = sum_s B[s,n]*decay[s]*X[s,p]
  const size_t csb = ((size_t)((b*NHEADS + h)*NCHUNK + c)) * (HEADDIM*DSTATE);
  for (int e = tid; e < HEADDIM*DSTATE; e += 256) {
    int p = e >> 7, n = e & 127;
    float a = 0.f;
    for (int s = 0; s < CHUNK; ++s)
      a += us2f(sB[s*130 + n]) * sdecay[s] * us2f(sX[s*66 + p]);
    cs[csb + e] = f2us(a);
  }
}

// ---- B: inter-chunk running-state scan (reference quirk: post-chunk state) ----
__global__ __launch_bounds__(256) void ssd_scan_states(
    unsigned short* __restrict__ cs, const float* __restrict__ acs) {
  int idx = blockIdx.x * 256 + threadIdx.x;   // over B*NH*HD*DS = 1,048,576
  int e  = idx & 8191;
  int bh = idx >> 13;
  float S = 0.f;
  for (int c = 0; c < NCHUNK; ++c) {
    float al = acs[((size_t)bh*NCHUNK + c)*64 + 63];
    size_t o = ((size_t)bh*NCHUNK + c)*(HEADDIM*DSTATE) + e;
    S = S * expf(al) + us2f(cs[o]);
    cs[o] = f2us(S);
  }
}

// ---- C: Y += (C . S) * exp(Ac) ----
__global__ __launch_bounds__(256) void ssd_phase_c(
    const unsigned short* __restrict__ bcact, const unsigned short* __restrict__ cs,
    const float* __restrict__ acs, unsigned short* __restrict__ yscan) {
  const int h = blockIdx.x & 63;
  const int c = (blockIdx.x >> 6) & 31;
  const int b = blockIdx.x >> 11;
  const int tid = threadIdx.x;
  const int t0 = b * SEQ + c * CHUNK;

  __shared__ unsigned short sS[64*130];
  __shared__ unsigned short sC[64*130];
  __shared__ float seAc[64];

  const size_t csb = ((size_t)((b*NHEADS + h)*NCHUNK + c)) * (HEADDIM*DSTATE);
  for (int i = tid; i < 8192; i += 256) {
    int p = i >> 7, n = i & 127;
    sS[p*130 + n] = cs[csb + i];
  }
  for (int i = tid; i < 8192; i += 256) {
    int s = i >> 7, n = i & 127;
    sC[s*130 + n] = bcact[(size_t)(t0 + s) * 256 + 128 + n];
  }
  if (tid < 64) seAc[tid] = expf(acs[((size_t)((b*NHEADS + h)*NCHUNK + c))*64 + tid]);
  __syncthreads();

  for (int o = tid; o < CHUNK*HEADDIM; o += 256) {
    int l = o >> 6, p = o & 63;
    float yo = 0.f;
    const uint32_t* Cu = (const uint32_t*)&sC[l * 130];
    const uint32_t* Su = (const uint32_t*)&sS[p * 130];
    for (int u = 0; u < 64; ++u) {
      uint32_t cv = Cu[u], sv = Su[u];
      yo += plo(cv) * plo(sv) + phi(cv) * phi(sv);
    }
    size_t yi = (size_t)(t0 + l) * DINNER + h*HEADDIM + p;
    yscan[yi] = f2us(us2f(yscan[yi]) + yo * seAc[l]);
  }
}

// ---- gating + RMSNorm (no conv; D-skip folded into phase A2) ----
__global__ __launch_bounds__(256) void gate_rmsnorm2(
    const unsigned short* __restrict__ proj, const float* __restrict__ norm_w,
    unsigned short* __restrict__ yscan) {
  const int t = blockIdx.x;
  const int tid = threadIdx.x;
  __shared__ float ybuf[DINNER];
  __shared__ float wpart[4];
  __shared__ float sinv;
  float ss = 0.f;
  for (int i = tid; i < DINNER; i += 256) {
    float zv = us2f(proj[(size_t)t * NPROJ + i]);
    float yv = us2f(yscan[(size_t)t * DINNER + i]) * (zv / (1.f + expf(-zv)));
    ybuf[i] = yv;
    ss += yv * yv;
  }
  #pragma unroll
  for (int off = 32; off > 0; off >>= 1) ss += __shfl_down(ss, off, 64);
  if ((tid & 63) == 0) wpart[tid >> 6] = ss;
  __syncthreads();
  if (tid == 0) {
    float tot = wpart[0] + wpart[1] + wpart[2] + wpart[3];
    sinv = 1.f / sqrtf(tot / (float)DINNER + 1e-5f);
  }
  __syncthreads();
  float inv = sinv;
  for (int i = tid; i < DINNER; i += 256)
    yscan[(size_t)t * DINNER + i] = f2us(ybuf[i] * inv * norm_w[i]);
}

// ================= FALLBACK path (round-1, proven; used if ws too small) ====
__global__ __launch_bounds__(512) void ssd_fused(
    const unsigned short* __restrict__ proj, const float* __restrict__ dtr,
    const float* __restrict__ cw, const float* __restrict__ cb,
    const float* __restrict__ A_log, const float* __restrict__ dt_bias,
    unsigned short* __restrict__ yscan) {
  const int h = blockIdx.x & 63;
  const int b = blockIdx.x >> 6;
  const int tid = threadIdx.x;

  __shared__ unsigned short sB[64*130];
  __shared__ unsigned short sC[64*130];
  __shared__ unsigned short sX[64*66];
  __shared__ float sW[64*65];
  __shared__ float sdt[64], sAc[64], sdecay[64], seAc[64];

  const float Ah = -expf(A_log[h]);
  const float dbias = dt_bias[h];

  float S[16];
  #pragma unroll
  for (int j = 0; j < 16; ++j) S[j] = 0.f;

  const int lG  = tid >> 3;
  const int oc  = tid & 7;

  for (int c = 0; c < NCHUNK; ++c) {
    const int t0 = b * SEQ + c * CHUNK;
    __syncthreads();
    if (tid < 64) {
      float raw = dtr[(size_t)(t0 + tid) * NHEADS + h] + dbias;
      sdt[tid] = (raw > 20.f) ? raw : log1pf(expf(raw));
    }
    for (int i = tid; i < 64*256; i += 512) {
      int s = i >> 8, ch = i & 255;
      int cx = 4096 + ch;
      int lb = c * CHUNK + s;
      float acc = cb[cx];
      #pragma unroll
      for (int j = 0; j < 4; ++j) {
        int ll = lb - 3 + j;
        if (ll >= 0)
          acc += cw[cx*4 + j] * us2f(proj[(size_t)(b*SEQ + ll) * NPROJ + DINNER + cx]);
      }
      float v = acc / (1.f + expf(-acc));
      if (ch < 128) sB[s*130 + ch] = f2us(v);
      else          sC[s*130 + (ch - 128)] = f2us(v);
    }
    __syncthreads();
    if (tid == 0) {
      float run = 0.f;
      for (int s = 0; s < CHUNK; ++s) { run += sdt[s] * Ah; sAc[s] = run; }
    }
    __syncthreads();
    if (tid < 64) {
      float last = sAc[63];
      sdecay[tid] = expf(last - sAc[tid]);
      seAc[tid]   = expf(sAc[tid]);
    }
    for (int i = tid; i < 64*64; i += 512) {
      int s = i >> 6, p = i & 63;
      int cx = h * HEADDIM + p;
      int lb = c * CHUNK + s;
      float acc = cb[cx];
      #pragma unroll
      for (int j = 0; j < 4; ++j) {
        int ll = lb - 3 + j;
        if (ll >= 0)
          acc += cw[cx*4 + j] * us2f(proj[(size_t)(b*SEQ + ll) * NPROJ + DINNER + cx]);
      }
      float v = acc / (1.f + expf(-acc));
      sX[s*66 + p] = f2us(v * sdt[s]);
    }
    __syncthreads();

    float g[8];
    #pragma unroll
    for (int j = 0; j < 8; ++j) g[j] = 0.f;
    {
      const uint32_t* Cu = (const uint32_t*)&sC[lG * 130];
      for (int u = 0; u < 64; ++u) {
        uint32_t cv = Cu[u];
        float c0 = plo(cv), c1 = phi(cv);
        #pragma unroll
        for (int j = 0; j < 8; ++j) {
          uint32_t bv = ((const uint32_t*)&sB[(oc*8 + j) * 130])[u];
          g[j] += c0 * plo(bv) + c1 * phi(bv);
        }
      }
    }
    {
      float acl = sAc[lG];
      #pragma unroll
      for (int j = 0; j < 8; ++j) {
        int s = oc*8 + j;
        sW[lG*65 + s] = (s <= lG) ? g[j] * expf(acl - sAc[s]) : 0.f;
      }
    }
    {
      float elast = expf(sAc[63]);
      #pragma unroll
      for (int j = 0; j < 16; ++j) S[j] *= elast;
      for (int s = 0; s < CHUNK; ++s) {
        float w = sdecay[s] * us2f(sX[s*66 + lG]);
        const uint32_t* Bu = (const uint32_t*)&sB[s*130 + oc*16];
        #pragma unroll
        for (int ju = 0; ju < 8; ++ju) {
          uint32_t bv = Bu[ju];
          S[2*ju]   += plo(bv) * w;
          S[2*ju+1] += phi(bv) * w;
        }
      }
    }
    __syncthreads();
    #pragma unroll
    for (int j = 0; j < 16; ++j) sB[lG*130 + oc*16 + j] = f2us(S[j]);
    __syncthreads();
    for (int o = tid; o < CHUNK*HEADDIM; o += 512) {
      int l = o >> 6, p = o & 63;
      float yd = 0.f;
      for (int s = 0; s <= l; ++s)
        yd += sW[l*65 + s] * us2f(sX[s*66 + p]);
      float yo = 0.f;
      const uint32_t* Cu = (const uint32_t*)&sC[l * 130];
      const uint32_t* Su = (const uint32_t*)&sB[p * 130];
      for (int u = 0; u < 64; ++u) {
        uint32_t cv = Cu[u], sv = Su[u];
        yo += plo(cv) * plo(sv) + phi(cv) * phi(sv);
      }
      float y = yd + yo * seAc[l];
      yscan[(size_t)(t0 + l) * DINNER + h * HEADDIM + p] = f2us(y);
    }
  }
}

__global__ __launch_bounds__(256) void gate_rmsnorm_dskip(
    const unsigned short* __restrict__ proj, const float* __restrict__ cw,
    const float* __restrict__ cb, const float* __restrict__ Dv,
    const float* __restrict__ norm_w, unsigned short* __restrict__ yscan) {
  const int t = blockIdx.x;
  const int tid = threadIdx.x;
  const int b = t >> 11, lb = t & 2047;
  __shared__ float ybuf[DINNER];
  __shared__ float wpart[4];
  __shared__ float sinv;
  float ss = 0.f;
  for (int i = tid; i < DINNER; i += 256) {
    float zv = us2f(proj[(size_t)t * NPROJ + i]);
    float acc = cb[i];
    #pragma unroll
    for (int j = 0; j < 4; ++j) {
      int ll = lb - 3 + j;
      if (ll >= 0)
        acc += cw[i*4 + j] * us2f(proj[(size_t)(b*SEQ + ll) * NPROJ + DINNER + i]);
    }
    float xh = acc / (1.f + expf(-acc));
    float yv = us2f(yscan[(size_t)t * DINNER + i]) + xh * Dv[i >> 6];
    yv = yv * (zv / (1.f + expf(-zv)));
    ybuf[i] = yv;
    ss += yv * yv;
  }
  #pragma unroll
  for (int off = 32; off > 0; off >>= 1) ss += __shfl_down(ss, off, 64);
  if ((tid & 63) == 0) wpart[tid >> 6] = ss;
  __syncthreads();
  if (tid == 0) {
    float tot = wpart[0] + wpart[1] + wpart[2] + wpart[3];
    sinv = 1.f / sqrtf(tot / (float)DINNER + 1e-5f);
  }
  __syncthreads();
  float inv = sinv;
  for (int i = tid; i < DINNER; i += 256)
    yscan[(size_t)t * DINNER + i] = f2us(ybuf[i] * inv * norm_w[i]);
}

// ---------------- launch ----------------
extern "C" void kernel_launch(void* const* d_in, const int* in_sizes, int n_in,
                              void* d_out, int out_size, void* d_ws, size_t ws_size,
                              hipStream_t stream) {
  const float* x          = (const float*)d_in[0];
  const float* in_proj_w  = (const float*)d_in[1];
  const float* conv_w     = (const float*)d_in[2];
  const float* conv_b     = (const float*)d_in[3];
  const float* A_log      = (const float*)d_in[4];
  const float* Dv         = (const float*)d_in[5];
  const float* dt_bias    = (const float*)d_in[6];
  const float* norm_w     = (const float*)d_in[7];
  const float* out_proj_w = (const float*)d_in[8];
  float* out = (float*)d_out;

  // ws carve-up
  unsigned short* proj  = (unsigned short*)d_ws;                         // TOKENS*NPROJ bf16
  float*          dtr   = (float*)(proj + (size_t)TOKENS * NPROJ);       // TOKENS*NHEADS f32
  unsigned short* yscan = (unsigned short*)(dtr + (size_t)TOKENS * NHEADS); // TOKENS*DINNER bf16
  unsigned short* cs    = yscan + (size_t)TOKENS * DINNER;               // 2*64*32*8192 bf16
  float*          acs   = (float*)(cs + (size_t)B_SZ*NHEADS*NCHUNK*HEADDIM*DSTATE); // f32
  unsigned short* bcact = (unsigned short*)(acs + (size_t)B_SZ*NHEADS*NCHUNK*64);
  float*          gbuf  = (float*)(bcact + (size_t)TOKENS*256);
  const size_t NEEDED = (size_t)((char*)(gbuf + (size_t)B_SZ*NCHUNK*4096) - (char*)d_ws);

  // 1) proj(z|xBC) = x @ in_proj_w[0:8448]^T -> bf16
  {
    dim3 grid(NPROJ/128, TOKENS/128);
    gemm_nt<float, unsigned short><<<grid, 256, 0, stream>>>(
        x, in_proj_w, proj, TOKENS, NPROJ, DMODEL);
  }
  // 2) dt_raw (fp32)
  dt_gemv<<<TOKENS, 256, 0, stream>>>(x, in_proj_w, dtr);

  if (ws_size >= NEEDED) {
    // 3) split scan, 4096-block phases
    bc_conv_g<<<B_SZ*NCHUNK, 256, 0, stream>>>(proj, conv_w, conv_b, bcact, gbuf);
    ssd_phase_a2<<<B_SZ*NCHUNK*NHEADS, 256, 0, stream>>>(
        proj, bcact, dtr, conv_w, conv_b, A_log, dt_bias, gbuf, Dv, cs, acs, yscan);
    ssd_scan_states<<<(B_SZ*NHEADS*HEADDIM*DSTATE)/256, 256, 0, stream>>>(cs, acs);
    ssd_phase_c<<<B_SZ*NCHUNK*NHEADS, 256, 0, stream>>>(bcact, cs, acs, yscan);
    gate_rmsnorm2<<<TOKENS, 256, 0, stream>>>(proj, norm_w, yscan);
  } else {
    // fallback: proven round-1 path (104 MB ws)
    ssd_fused<<<B_SZ*NHEADS, 512, 0, stream>>>(proj, dtr, conv_w, conv_b,
                                               A_log, dt_bias, yscan);
    gate_rmsnorm_dskip<<<TOKENS, 256, 0, stream>>>(proj, conv_w, conv_b, Dv, norm_w, yscan);
  }

  // 5) out = yn @ out_proj_w^T (fp32 out)
  {
    dim3 grid(DMODEL/128, TOKENS/128);
    gemm_nt<unsigned short, float><<<grid, 256, 0, stream>>>(
        yscan, out_proj_w, out, TOKENS, DMODEL, DINNER);
  }
}

// Round 4
// 1478.001 us; speedup vs baseline: 3.9500x; 2.6577x over previous
//
#include <hip/hip_runtime.h>
#include <cstddef>
#include <cstdint>

// ---------------- problem constants ----------------
#define B_SZ    2
#define SEQ     2048
#define DMODEL  2048
#define DINNER  4096
#define DSTATE  128
#define NHEADS  64
#define HEADDIM 64
#define DXBC    4352          // DINNER + 2*DSTATE
#define NPROJ   8448          // DINNER + DXBC (z | xBC); dt handled separately in fp32
#define CHUNK   64
#define NCHUNK  32
#define TOKENS  (B_SZ*SEQ)    // 4096

typedef __attribute__((ext_vector_type(8))) short short8;   // 8 x bf16
typedef __attribute__((ext_vector_type(4))) float floatx4;

// ---- bf16 <-> f32 helpers ----
__device__ inline float us2f(unsigned short u) {
  union { uint32_t i; float f; } c; c.i = ((uint32_t)u) << 16; return c.f;
}
__device__ inline unsigned short f2us(float f) {
  union { float f; uint32_t i; } c; c.f = f;
  uint32_t r = (c.i + 0x7fffu + ((c.i >> 16) & 1u)) >> 16;
  return (unsigned short)r;
}
__device__ inline float plo(uint32_t v) {
  union { uint32_t i; float f; } c; c.i = v << 16; return c.f;
}
__device__ inline float phi(uint32_t v) {
  union { uint32_t i; float f; } c; c.i = v & 0xffff0000u; return c.f;
}

// ---------------- f32 -> bf16 cast (vectorized) ----------------
__global__ __launch_bounds__(256) void cast_f32_bf16(
    const float* __restrict__ src, unsigned short* __restrict__ dst, int n) {
  int i = (blockIdx.x * 256 + threadIdx.x) * 4;
  if (i < n) {
    float4 v = *(const float4*)(src + i);
    ushort4 o;
    o.x = f2us(v.x); o.y = f2us(v.y); o.z = f2us(v.z); o.w = f2us(v.w);
    *(ushort4*)(dst + i) = o;
  }
}

// ---------------- MFMA bf16 NT GEMM: C[M,N] = A[M,K] @ B[N,K]^T ----------------
// 128x128 tile, BK=32, 256 threads (4 waves), wave = 64x64 via 4x4 mfma_16x16x32.
// M,N % 128 == 0, K % 32 == 0. OUT_BF16: 1 -> bf16 store, 0 -> f32 store.
template<int OUT_BF16>
__global__ __launch_bounds__(256) void gemm_bt_mfma(
    const unsigned short* __restrict__ A, const unsigned short* __restrict__ B,
    void* __restrict__ Cout, int M, int N, int K) {
  __shared__ unsigned short sA[128*32];
  __shared__ unsigned short sB[128*32];
  const int tid  = threadIdx.x;
  const int lane = tid & 63;
  const int wave = tid >> 6;
  const int bm = blockIdx.y * 128;
  const int bn = blockIdx.x * 128;
  const int wm = (wave >> 1) * 64;
  const int wn = (wave & 1) * 64;
  const int fr = lane & 15;          // fragment row (m or n within 16)
  const int fq = lane >> 4;          // quad: k-offset = fq*8

  floatx4 acc[4][4];
  #pragma unroll
  for (int i = 0; i < 4; ++i)
    #pragma unroll
    for (int j = 0; j < 4; ++j) acc[i][j] = (floatx4){0.f, 0.f, 0.f, 0.f};

  // staging: per issue, 256 threads x 16 B = 4 KB; A/B tiles are 8 KB each -> 2+2 issues
  const int g0 = tid * 8;            // element offset of this thread's 16B
  for (int k0 = 0; k0 < K; k0 += 32) {
    __syncthreads();                 // protect LDS from previous iteration's readers
    #pragma unroll
    for (int r = 0; r < 2; ++r) {
      int g = r * 2048 + g0;
      int row = g >> 5, col = g & 31;
      const unsigned short* gp = A + (size_t)(bm + row) * K + k0 + col;
      __builtin_amdgcn_global_load_lds(
          (const __attribute__((address_space(1))) uint32_t*)gp,
          (__attribute__((address_space(3))) uint32_t*)(sA + g), 16, 0, 0);
    }
    #pragma unroll
    for (int r = 0; r < 2; ++r) {
      int g = r * 2048 + g0;
      int row = g >> 5, col = g & 31;
      const unsigned short* gp = B + (size_t)(bn + row) * K + k0 + col;
      __builtin_amdgcn_global_load_lds(
          (const __attribute__((address_space(1))) uint32_t*)gp,
          (__attribute__((address_space(3))) uint32_t*)(sB + g), 16, 0, 0);
    }
    __syncthreads();                 // compiler emits vmcnt(0) drain before barrier

    short8 af[4], bfr[4];
    #pragma unroll
    for (int i = 0; i < 4; ++i)
      af[i] = *(const short8*)(sA + (wm + i*16 + fr) * 32 + fq * 8);
    #pragma unroll
    for (int j = 0; j < 4; ++j)
      bfr[j] = *(const short8*)(sB + (wn + j*16 + fr) * 32 + fq * 8);
    #pragma unroll
    for (int i = 0; i < 4; ++i)
      #pragma unroll
      for (int j = 0; j < 4; ++j)
        acc[i][j] = __builtin_amdgcn_mfma_f32_16x16x32_bf16(af[i], bfr[j], acc[i][j], 0, 0, 0);
  }

  // epilogue: C/D layout col=lane&15, row=(lane>>4)*4+reg
  #pragma unroll
  for (int i = 0; i < 4; ++i) {
    #pragma unroll
    for (int j = 0; j < 4; ++j) {
      int col = bn + wn + j*16 + fr;
      #pragma unroll
      for (int r = 0; r < 4; ++r) {
        int row = bm + wm + i*16 + fq*4 + r;
        if (OUT_BF16)
          ((unsigned short*)Cout)[(size_t)row * N + col] = f2us(acc[i][j][r]);
        else
          ((float*)Cout)[(size_t)row * N + col] = acc[i][j][r];
      }
    }
  }
}

// ---------------- fp32 tiled NT GEMM (fallback path only) ----------------
__device__ inline void loadA4(const float* p, float* d) {
  float4 v = *(const float4*)p; d[0]=v.x; d[1]=v.y; d[2]=v.z; d[3]=v.w;
}
__device__ inline void loadA4(const unsigned short* p, float* d) {
  ushort4 v = *(const ushort4*)p;
  d[0]=us2f(v.x); d[1]=us2f(v.y); d[2]=us2f(v.z); d[3]=us2f(v.w);
}
__device__ inline void store8(float* C, size_t off, const float* v) {
  *(float4*)(C + off)     = make_float4(v[0], v[1], v[2], v[3]);
  *(float4*)(C + off + 4) = make_float4(v[4], v[5], v[6], v[7]);
}
__device__ inline void store8(unsigned short* C, size_t off, const float* v) {
  ushort4 a; a.x=f2us(v[0]); a.y=f2us(v[1]); a.z=f2us(v[2]); a.w=f2us(v[3]);
  ushort4 b; b.x=f2us(v[4]); b.y=f2us(v[5]); b.z=f2us(v[6]); b.w=f2us(v[7]);
  *(ushort4*)(C + off) = a; *(ushort4*)(C + off + 4) = b;
}

template<typename AT, typename OT>
__global__ __launch_bounds__(256) void gemm_nt(
    const AT* __restrict__ A, const float* __restrict__ Bw,
    OT* __restrict__ C, int M, int N, int K) {
  __shared__ float As[16][128+4];
  __shared__ float Bs[16][128+4];
  const int bm = blockIdx.y * 128;
  const int bn = blockIdx.x * 128;
  const int tid = threadIdx.x;
  const int tx = tid & 15, ty = tid >> 4;

  float acc[8][8];
  #pragma unroll
  for (int i = 0; i < 8; ++i)
    #pragma unroll
    for (int j = 0; j < 8; ++j) acc[i][j] = 0.f;

  for (int k0 = 0; k0 < K; k0 += 16) {
    #pragma unroll
    for (int r = 0; r < 2; ++r) {
      int i = tid + r * 256;
      int m  = i >> 2;
      int kv = (i & 3) << 2;
      float va[4];
      loadA4(A + (size_t)(bm + m) * K + k0 + kv, va);
      As[kv+0][m] = va[0]; As[kv+1][m] = va[1]; As[kv+2][m] = va[2]; As[kv+3][m] = va[3];
      float vb[4] = {0.f, 0.f, 0.f, 0.f};
      if (bn + m < N) loadA4(Bw + (size_t)(bn + m) * K + k0 + kv, vb);
      Bs[kv+0][m] = vb[0]; Bs[kv+1][m] = vb[1]; Bs[kv+2][m] = vb[2]; Bs[kv+3][m] = vb[3];
    }
    __syncthreads();
    #pragma unroll
    for (int kk = 0; kk < 16; ++kk) {
      float ra[8], rb[8];
      *(float4*)&ra[0] = *(const float4*)&As[kk][ty*8];
      *(float4*)&ra[4] = *(const float4*)&As[kk][ty*8+4];
      *(float4*)&rb[0] = *(const float4*)&Bs[kk][tx*8];
      *(float4*)&rb[4] = *(const float4*)&Bs[kk][tx*8+4];
      #pragma unroll
      for (int i = 0; i < 8; ++i)
        #pragma unroll
        for (int j = 0; j < 8; ++j) acc[i][j] += ra[i] * rb[j];
    }
    __syncthreads();
  }
  #pragma unroll
  for (int i = 0; i < 8; ++i) {
    int m  = bm + ty*8 + i;
    int n0 = bn + tx*8;
    if (n0 < N) store8(C, (size_t)m * N + n0, &acc[i][0]);
  }
}

// ---------------- dt GEMV (fp32) ----------------
__global__ __launch_bounds__(256) void dt_gemv(
    const float* __restrict__ x, const float* __restrict__ W,
    float* __restrict__ dtr) {
  const int t = blockIdx.x;
  const int tid = threadIdx.x;
  __shared__ float xrow[DMODEL];
  for (int i = tid; i < DMODEL; i += 256) xrow[i] = x[(size_t)t * DMODEL + i];
  __syncthreads();
  const int h = tid >> 2, q = tid & 3;
  const float4* wp = (const float4*)(W + (size_t)(NPROJ + h) * DMODEL + q * 512);
  const float4* xp = (const float4*)(xrow + q * 512);
  float acc = 0.f;
  #pragma unroll 4
  for (int u = 0; u < 128; ++u) {
    float4 a = xp[u], b = wp[u];
    acc += a.x*b.x + a.y*b.y + a.z*b.z + a.w*b.w;
  }
  acc += __shfl_xor(acc, 1, 64);
  acc += __shfl_xor(acc, 2, 64);
  if (q == 0) dtr[(size_t)t * NHEADS + h] = acc;
}

// ================= split-scan path =================
__global__ __launch_bounds__(256) void bc_conv_g(
    const unsigned short* __restrict__ proj, const float* __restrict__ cw,
    const float* __restrict__ cb, unsigned short* __restrict__ bcact,
    float* __restrict__ gbuf) {
  const int c = blockIdx.x & 31;
  const int b = blockIdx.x >> 5;
  const int tid = threadIdx.x;
  const int t0 = b * SEQ + c * CHUNK;
  __shared__ unsigned short sB[64*130];
  __shared__ unsigned short sC[64*130];
  for (int i = tid; i < 64*256; i += 256) {
    int s = i >> 8, ch = i & 255;
    int cx = 4096 + ch;
    int lb = c * CHUNK + s;
    float acc = cb[cx];
    #pragma unroll
    for (int j = 0; j < 4; ++j) {
      int ll = lb - 3 + j;
      if (ll >= 0)
        acc += cw[cx*4 + j] * us2f(proj[(size_t)(b*SEQ + ll) * NPROJ + DINNER + cx]);
    }
    float v = acc / (1.f + expf(-acc));
    unsigned short uv = f2us(v);
    if (ch < 128) sB[s*130 + ch] = uv;
    else          sC[s*130 + (ch - 128)] = uv;
    bcact[(size_t)(t0 + s) * 256 + ch] = uv;
  }
  __syncthreads();
  const int l = tid >> 2, q = tid & 3;
  float g[16];
  #pragma unroll
  for (int j = 0; j < 16; ++j) g[j] = 0.f;
  const uint32_t* Cu = (const uint32_t*)&sC[l * 130];
  for (int u = 0; u < 64; ++u) {
    uint32_t cv = Cu[u];
    float c0 = plo(cv), c1 = phi(cv);
    #pragma unroll
    for (int j = 0; j < 16; ++j) {
      uint32_t bv = ((const uint32_t*)&sB[(q*16 + j) * 130])[u];
      g[j] += c0 * plo(bv) + c1 * phi(bv);
    }
  }
  float* gr = gbuf + ((size_t)(b*NCHUNK + c)) * 4096 + l*64 + q*16;
  #pragma unroll
  for (int j = 0; j < 16; ++j) gr[j] = g[j];
}

__global__ __launch_bounds__(256) void ssd_phase_a2(
    const unsigned short* __restrict__ proj, const unsigned short* __restrict__ bcact,
    const float* __restrict__ dtr, const float* __restrict__ cw,
    const float* __restrict__ cb, const float* __restrict__ A_log,
    const float* __restrict__ dt_bias, const float* __restrict__ gbuf,
    const float* __restrict__ Dv,
    unsigned short* __restrict__ cs, float* __restrict__ acs,
    unsigned short* __restrict__ yscan) {
  const int h = blockIdx.x & 63;
  const int c = (blockIdx.x >> 6) & 31;
  const int b = blockIdx.x >> 11;
  const int tid = threadIdx.x;
  const int t0 = b * SEQ + c * CHUNK;

  __shared__ unsigned short sB[64*130];
  __shared__ unsigned short sX[64*66];
  __shared__ unsigned short sXh[64*66];
  __shared__ float sW[64*65];
  __shared__ float sdt[64], sAc[64], sdecay[64];

  const float Ah = -expf(A_log[h]);
  if (tid < 64) {
    float raw = dtr[(size_t)(t0 + tid) * NHEADS + h] + dt_bias[h];
    float dt = (raw > 20.f) ? raw : log1pf(expf(raw));
    sdt[tid] = dt;
    float v = dt * Ah;
    #pragma unroll
    for (int off = 1; off < 64; off <<= 1) {
      float o = __shfl_up(v, off, 64);
      if (tid >= off) v += o;
    }
    sAc[tid] = v;
    acs[((size_t)((b*NHEADS + h)*NCHUNK + c))*64 + tid] = v;
  }
  for (int i = tid; i < 64*128; i += 256) {
    int s = i >> 7, n = i & 127;
    sB[s*130 + n] = bcact[(size_t)(t0 + s) * 256 + n];
  }
  __syncthreads();
  const float alast = sAc[63];
  if (tid < 64) sdecay[tid] = expf(alast - sAc[tid]);
  for (int i = tid; i < 64*64; i += 256) {
    int s = i >> 6, p = i & 63;
    int cx = h * HEADDIM + p;
    int lb = c * CHUNK + s;
    float acc = cb[cx];
    #pragma unroll
    for (int j = 0; j < 4; ++j) {
      int ll = lb - 3 + j;
      if (ll >= 0)
        acc += cw[cx*4 + j] * us2f(proj[(size_t)(b*SEQ + ll) * NPROJ + DINNER + cx]);
    }
    float xh = acc / (1.f + expf(-acc));
    sXh[s*66 + p] = f2us(xh);
    sX[s*66 + p]  = f2us(xh * sdt[s]);
  }
  {
    const float* gr = gbuf + ((size_t)(b*NCHUNK + c)) * 4096;
    for (int i = tid; i < 4096; i += 256) {
      int l = i >> 6, s = i & 63;
      sW[l*65 + s] = (s <= l) ? gr[i] * expf(sAc[l] - sAc[s]) : 0.f;
    }
  }
  __syncthreads();

  const float Dh = Dv[h];
  for (int o = tid; o < CHUNK*HEADDIM; o += 256) {
    int l = o >> 6, p = o & 63;
    float yd = 0.f;
    for (int s = 0; s <= l; ++s) yd += sW[l*65 + s] * us2f(sX[s*66 + p]);
    yd += us2f(sXh[l*66 + p]) * Dh;
    yscan[(size_t)(t0 + l) * DINNER + h*HEADDIM + p] = f2us(yd);
  }
  const size_t csb = ((size_t)((b*NHEADS + h)*NCHUNK + c)) * (HEADDIM*DSTATE);
  for (int e = tid; e < HEADDIM*DSTATE; e += 256) {
    int p = e >> 7, n = e & 127;
    float a = 0.f;
    for (int s = 0; s < CHUNK; ++s)
      a += us2f(sB[s*130 + n]) * sdecay[s] * us2f(sX[s*66 + p]);
    cs[csb + e] = f2us(a);
  }
}

__global__ __launch_bounds__(256) void ssd_scan_states(
    unsigned short* __restrict__ cs, const float* __restrict__ acs) {
  int idx = blockIdx.x * 256 + threadIdx.x;
  int e  = idx & 8191;
  int bh = idx >> 13;
  float S = 0.f;
  for (int c = 0; c < NCHUNK; ++c) {
    float al = acs[((size_t)bh*NCHUNK + c)*64 + 63];
    size_t o = ((size_t)bh*NCHUNK + c)*(HEADDIM*DSTATE) + e;
    S = S * expf(al) + us2f(cs[o]);
    cs[o] = f2us(S);
  }
}

__global__ __launch_bounds__(256) void ssd_phase_c(
    const unsigned short* __restrict__ bcact, const unsigned short* __restrict__ cs,
    const float* __restrict__ acs, unsigned short* __restrict__ yscan) {
  const int h = blockIdx.x & 63;
  const int c = (blockIdx.x >> 6) & 31;
  const int b = blockIdx.x >> 11;
  const int tid = threadIdx.x;
  const int t0 = b * SEQ + c * CHUNK;

  __shared__ unsigned short sS[64*130];
  __shared__ unsigned short sC[64*130];
  __shared__ float seAc[64];

  const size_t csb = ((size_t)((b*NHEADS + h)*NCHUNK + c)) * (HEADDIM*DSTATE);
  for (int i = tid; i < 8192; i += 256) {
    int p = i >> 7, n = i & 127;
    sS[p*130 + n] = cs[csb + i];
  }
  for (int i = tid; i < 8192; i += 256) {
    int s = i >> 7, n = i & 127;
    sC[s*130 + n] = bcact[(size_t)(t0 + s) * 256 + 128 + n];
  }
  if (tid < 64) seAc[tid] = expf(acs[((size_t)((b*NHEADS + h)*NCHUNK + c))*64 + tid]);
  __syncthreads();

  for (int o = tid; o < CHUNK*HEADDIM; o += 256) {
    int l = o >> 6, p = o & 63;
    float yo = 0.f;
    const uint32_t* Cu = (const uint32_t*)&sC[l * 130];
    const uint32_t* Su = (const uint32_t*)&sS[p * 130];
    for (int u = 0; u < 64; ++u) {
      uint32_t cv = Cu[u], sv = Su[u];
      yo += plo(cv) * plo(sv) + phi(cv) * phi(sv);
    }
    size_t yi = (size_t)(t0 + l) * DINNER + h*HEADDIM + p;
    yscan[yi] = f2us(us2f(yscan[yi]) + yo * seAc[l]);
  }
}

__global__ __launch_bounds__(256) void gate_rmsnorm2(
    const unsigned short* __restrict__ proj, const float* __restrict__ norm_w,
    unsigned short* __restrict__ yscan) {
  const int t = blockIdx.x;
  const int tid = threadIdx.x;
  __shared__ float ybuf[DINNER];
  __shared__ float wpart[4];
  __shared__ float sinv;
  float ss = 0.f;
  for (int i = tid; i < DINNER; i += 256) {
    float zv = us2f(proj[(size_t)t * NPROJ + i]);
    float yv = us2f(yscan[(size_t)t * DINNER + i]) * (zv / (1.f + expf(-zv)));
    ybuf[i] = yv;
    ss += yv * yv;
  }
  #pragma unroll
  for (int off = 32; off > 0; off >>= 1) ss += __shfl_down(ss, off, 64);
  if ((tid & 63) == 0) wpart[tid >> 6] = ss;
  __syncthreads();
  if (tid == 0) {
    float tot = wpart[0] + wpart[1] + wpart[2] + wpart[3];
    sinv = 1.f / sqrtf(tot / (float)DINNER + 1e-5f);
  }
  __syncthreads();
  float inv = sinv;
  for (int i = tid; i < DINNER; i += 256)
    yscan[(size_t)t * DINNER + i] = f2us(ybuf[i] * inv * norm_w[i]);
}

// ================= FALLBACK path (round-1, proven; used if ws too small) ====
__global__ __launch_bounds__(512) void ssd_fused(
    const unsigned short* __restrict__ proj, const float* __restrict__ dtr,
    const float* __restrict__ cw, const float* __restrict__ cb,
    const float* __restrict__ A_log, const float* __restrict__ dt_bias,
    unsigned short* __restrict__ yscan) {
  const int h = blockIdx.x & 63;
  const int b = blockIdx.x >> 6;
  const int tid = threadIdx.x;

  __shared__ unsigned short sB[64*130];
  __shared__ unsigned short sC[64*130];
  __shared__ unsigned short sX[64*66];
  __shared__ float sW[64*65];
  __shared__ float sdt[64], sAc[64], sdecay[64], seAc[64];

  const float Ah = -expf(A_log[h]);
  const float dbias = dt_bias[h];

  float S[16];
  #pragma unroll
  for (int j = 0; j < 16; ++j) S[j] = 0.f;

  const int lG  = tid >> 3;
  const int oc  = tid & 7;

  for (int c = 0; c < NCHUNK; ++c) {
    const int t0 = b * SEQ + c * CHUNK;
    __syncthreads();
    if (tid < 64) {
      float raw = dtr[(size_t)(t0 + tid) * NHEADS + h] + dbias;
      sdt[tid] = (raw > 20.f) ? raw : log1pf(expf(raw));
    }
    for (int i = tid; i < 64*256; i += 512) {
      int s = i >> 8, ch = i & 255;
      int cx = 4096 + ch;
      int lb = c * CHUNK + s;
      float acc = cb[cx];
      #pragma unroll
      for (int j = 0; j < 4; ++j) {
        int ll = lb - 3 + j;
        if (ll >= 0)
          acc += cw[cx*4 + j] * us2f(proj[(size_t)(b*SEQ + ll) * NPROJ + DINNER + cx]);
      }
      float v = acc / (1.f + expf(-acc));
      if (ch < 128) sB[s*130 + ch] = f2us(v);
      else          sC[s*130 + (ch - 128)] = f2us(v);
    }
    __syncthreads();
    if (tid == 0) {
      float run = 0.f;
      for (int s = 0; s < CHUNK; ++s) { run += sdt[s] * Ah; sAc[s] = run; }
    }
    __syncthreads();
    if (tid < 64) {
      float last = sAc[63];
      sdecay[tid] = expf(last - sAc[tid]);
      seAc[tid]   = expf(sAc[tid]);
    }
    for (int i = tid; i < 64*64; i += 512) {
      int s = i >> 6, p = i & 63;
      int cx = h * HEADDIM + p;
      int lb = c * CHUNK + s;
      float acc = cb[cx];
      #pragma unroll
      for (int j = 0; j < 4; ++j) {
        int ll = lb - 3 + j;
        if (ll >= 0)
          acc += cw[cx*4 + j] * us2f(proj[(size_t)(b*SEQ + ll) * NPROJ + DINNER + cx]);
      }
      float v = acc / (1.f + expf(-acc));
      sX[s*66 + p] = f2us(v * sdt[s]);
    }
    __syncthreads();

    float g[8];
    #pragma unroll
    for (int j = 0; j < 8; ++j) g[j] = 0.f;
    {
      const uint32_t* Cu = (const uint32_t*)&sC[lG * 130];
      for (int u = 0; u < 64; ++u) {
        uint32_t cv = Cu[u];
        float c0 = plo(cv), c1 = phi(cv);
        #pragma unroll
        for (int j = 0; j < 8; ++j) {
          uint32_t bv = ((const uint32_t*)&sB[(oc*8 + j) * 130])[u];
          g[j] += c0 * plo(bv) + c1 * phi(bv);
        }
      }
    }
    {
      float acl = sAc[lG];
      #pragma unroll
      for (int j = 0; j < 8; ++j) {
        int s = oc*8 + j;
        sW[lG*65 + s] = (s <= lG) ? g[j] * expf(acl - sAc[s]) : 0.f;
      }
    }
    {
      float elast = expf(sAc[63]);
      #pragma unroll
      for (int j = 0; j < 16; ++j) S[j] *= elast;
      for (int s = 0; s < CHUNK; ++s) {
        float w = sdecay[s] * us2f(sX[s*66 + lG]);
        const uint32_t* Bu = (const uint32_t*)&sB[s*130 + oc*16];
        #pragma unroll
        for (int ju = 0; ju < 8; ++ju) {
          uint32_t bv = Bu[ju];
          S[2*ju]   += plo(bv) * w;
          S[2*ju+1] += phi(bv) * w;
        }
      }
    }
    __syncthreads();
    #pragma unroll
    for (int j = 0; j < 16; ++j) sB[lG*130 + oc*16 + j] = f2us(S[j]);
    __syncthreads();
    for (int o = tid; o < CHUNK*HEADDIM; o += 512) {
      int l = o >> 6, p = o & 63;
      float yd = 0.f;
      for (int s = 0; s <= l; ++s)
        yd += sW[l*65 + s] * us2f(sX[s*66 + p]);
      float yo = 0.f;
      const uint32_t* Cu = (const uint32_t*)&sC[l * 130];
      const uint32_t* Su = (const uint32_t*)&sB[p * 130];
      for (int u = 0; u < 64; ++u) {
        uint32_t cv = Cu[u], sv = Su[u];
        yo += plo(cv) * plo(sv) + phi(cv) * phi(sv);
      }
      float y = yd + yo * seAc[l];
      yscan[(size_t)(t0 + l) * DINNER + h * HEADDIM + p] = f2us(y);
    }
  }
}

__global__ __launch_bounds__(256) void gate_rmsnorm_dskip(
    const unsigned short* __restrict__ proj, const float* __restrict__ cw,
    const float* __restrict__ cb, const float* __restrict__ Dv,
    const float* __restrict__ norm_w, unsigned short* __restrict__ yscan) {
  const int t = blockIdx.x;
  const int tid = threadIdx.x;
  const int b = t >> 11, lb = t & 2047;
  __shared__ float ybuf[DINNER];
  __shared__ float wpart[4];
  __shared__ float sinv;
  float ss = 0.f;
  for (int i = tid; i < DINNER; i += 256) {
    float zv = us2f(proj[(size_t)t * NPROJ + i]);
    float acc = cb[i];
    #pragma unroll
    for (int j = 0; j < 4; ++j) {
      int ll = lb - 3 + j;
      if (ll >= 0)
        acc += cw[i*4 + j] * us2f(proj[(size_t)(b*SEQ + ll) * NPROJ + DINNER + i]);
    }
    float xh = acc / (1.f + expf(-acc));
    float yv = us2f(yscan[(size_t)t * DINNER + i]) + xh * Dv[i >> 6];
    yv = yv * (zv / (1.f + expf(-zv)));
    ybuf[i] = yv;
    ss += yv * yv;
  }
  #pragma unroll
  for (int off = 32; off > 0; off >>= 1) ss += __shfl_down(ss, off, 64);
  if ((tid & 63) == 0) wpart[tid >> 6] = ss;
  __syncthreads();
  if (tid == 0) {
    float tot = wpart[0] + wpart[1] + wpart[2] + wpart[3];
    sinv = 1.f / sqrtf(tot / (float)DINNER + 1e-5f);
  }
  __syncthreads();
  float inv = sinv;
  for (int i = tid; i < DINNER; i += 256)
    yscan[(size_t)t * DINNER + i] = f2us(ybuf[i] * inv * norm_w[i]);
}

// ---------------- launch ----------------
extern "C" void kernel_launch(void* const* d_in, const int* in_sizes, int n_in,
                              void* d_out, int out_size, void* d_ws, size_t ws_size,
                              hipStream_t stream) {
  const float* x          = (const float*)d_in[0];
  const float* in_proj_w  = (const float*)d_in[1];
  const float* conv_w     = (const float*)d_in[2];
  const float* conv_b     = (const float*)d_in[3];
  const float* A_log      = (const float*)d_in[4];
  const float* Dv         = (const float*)d_in[5];
  const float* dt_bias    = (const float*)d_in[6];
  const float* norm_w     = (const float*)d_in[7];
  const float* out_proj_w = (const float*)d_in[8];
  float* out = (float*)d_out;

  // ws carve-up (identical footprint to round 2)
  unsigned short* proj  = (unsigned short*)d_ws;                         // TOKENS*NPROJ bf16
  float*          dtr   = (float*)(proj + (size_t)TOKENS * NPROJ);       // TOKENS*NHEADS f32
  unsigned short* yscan = (unsigned short*)(dtr + (size_t)TOKENS * NHEADS); // TOKENS*DINNER bf16
  unsigned short* cs    = yscan + (size_t)TOKENS * DINNER;               // 2*64*32*8192 bf16
  float*          acs   = (float*)(cs + (size_t)B_SZ*NHEADS*NCHUNK*HEADDIM*DSTATE);
  unsigned short* bcact = (unsigned short*)(acs + (size_t)B_SZ*NHEADS*NCHUNK*64);
  float*          gbuf  = (float*)(bcact + (size_t)TOKENS*256);
  const size_t NEEDED = (size_t)((char*)(gbuf + (size_t)B_SZ*NCHUNK*4096) - (char*)d_ws);

  // bf16 cast buffers ALIAS dead regions:
  //   xb+wib (51.4 MB) live only before the scan -> overlay cs (64 MB, written later)
  //   wob (16.8 MB) live only after gate_rmsnorm2 -> overlay proj (dead by then)
  unsigned short* xb  = cs;                                  // TOKENS*DMODEL
  unsigned short* wib = xb + (size_t)TOKENS * DMODEL;        // NPROJ*DMODEL
  unsigned short* wob = proj;                                // DMODEL*DINNER

  if (ws_size >= NEEDED) {
    // 1) cast x and in_proj_w[0:8448] to bf16 (into cs region)
    cast_f32_bf16<<<(TOKENS*DMODEL)/1024, 256, 0, stream>>>(x, xb, TOKENS*DMODEL);
    cast_f32_bf16<<<((size_t)NPROJ*DMODEL)/1024, 256, 0, stream>>>(in_proj_w, wib, NPROJ*DMODEL);
    // 2) proj = xb @ wib^T via MFMA -> bf16
    {
      dim3 grid(NPROJ/128, TOKENS/128);   // 66 x 32
      gemm_bt_mfma<1><<<grid, 256, 0, stream>>>(xb, wib, proj, TOKENS, NPROJ, DMODEL);
    }
    // 3) dt_raw fp32 (precision-critical)
    dt_gemv<<<TOKENS, 256, 0, stream>>>(x, in_proj_w, dtr);
    // 4) split scan (phase_a2 overwrites cs -> xb/wib dead by then)
    bc_conv_g<<<B_SZ*NCHUNK, 256, 0, stream>>>(proj, conv_w, conv_b, bcact, gbuf);
    ssd_phase_a2<<<B_SZ*NCHUNK*NHEADS, 256, 0, stream>>>(
        proj, bcact, dtr, conv_w, conv_b, A_log, dt_bias, gbuf, Dv, cs, acs, yscan);
    ssd_scan_states<<<(B_SZ*NHEADS*HEADDIM*DSTATE)/256, 256, 0, stream>>>(cs, acs);
    ssd_phase_c<<<B_SZ*NCHUNK*NHEADS, 256, 0, stream>>>(bcact, cs, acs, yscan);
    gate_rmsnorm2<<<TOKENS, 256, 0, stream>>>(proj, norm_w, yscan);
    // 5) cast out_proj_w to bf16 (into proj region, now dead) and final MFMA GEMM
    cast_f32_bf16<<<((size_t)DMODEL*DINNER)/1024, 256, 0, stream>>>(out_proj_w, wob, DMODEL*DINNER);
    {
      dim3 grid(DMODEL/128, TOKENS/128);  // 16 x 32
      gemm_bt_mfma<0><<<grid, 256, 0, stream>>>(yscan, wob, out, TOKENS, DMODEL, DINNER);
    }
  } else {
    // fallback: proven round-1 path (104 MB ws), fp32 vector GEMMs
    {
      dim3 grid(NPROJ/128, TOKENS/128);
      gemm_nt<float, unsigned short><<<grid, 256, 0, stream>>>(
          x, in_proj_w, proj, TOKENS, NPROJ, DMODEL);
    }
    dt_gemv<<<TOKENS, 256, 0, stream>>>(x, in_proj_w, dtr);
    ssd_fused<<<B_SZ*NHEADS, 512, 0, stream>>>(proj, dtr, conv_w, conv_b,
                                               A_log, dt_bias, yscan);
    gate_rmsnorm_dskip<<<TOKENS, 256, 0, stream>>>(proj, conv_w, conv_b, Dv, norm_w, yscan);
    {
      dim3 grid(DMODEL/128, TOKENS/128);
      gemm_nt<unsigned short, float><<<grid, 256, 0, stream>>>(
          yscan, out_proj_w, out, TOKENS, DMODEL, DINNER);
    }
  }
}

// Round 5
// 964.169 us; speedup vs baseline: 6.0551x; 1.5329x over previous
//
#include <hip/hip_runtime.h>
#include <cstddef>
#include <cstdint>

// ---------------- problem constants ----------------
#define B_SZ    2
#define SEQ     2048
#define DMODEL  2048
#define DINNER  4096
#define DSTATE  128
#define NHEADS  64
#define HEADDIM 64
#define DXBC    4352          // DINNER + 2*DSTATE
#define NPROJ   8448          // DINNER + DXBC (z | xBC); dt handled separately in fp32
#define CHUNK   64
#define NCHUNK  32
#define TOKENS  (B_SZ*SEQ)    // 4096

typedef __attribute__((ext_vector_type(8))) short short8;   // 8 x bf16
typedef __attribute__((ext_vector_type(4))) float floatx4;

// ---- bf16 <-> f32 helpers ----
__device__ inline float us2f(unsigned short u) {
  union { uint32_t i; float f; } c; c.i = ((uint32_t)u) << 16; return c.f;
}
__device__ inline unsigned short f2us(float f) {
  union { float f; uint32_t i; } c; c.f = f;
  uint32_t r = (c.i + 0x7fffu + ((c.i >> 16) & 1u)) >> 16;
  return (unsigned short)r;
}
__device__ inline float plo(uint32_t v) {
  union { uint32_t i; float f; } c; c.i = v << 16; return c.f;
}
__device__ inline float phi(uint32_t v) {
  union { uint32_t i; float f; } c; c.i = v & 0xffff0000u; return c.f;
}

// ---------------- f32 -> bf16 cast (vectorized) ----------------
__global__ __launch_bounds__(256) void cast_f32_bf16(
    const float* __restrict__ src, unsigned short* __restrict__ dst, int n) {
  int i = (blockIdx.x * 256 + threadIdx.x) * 4;
  if (i < n) {
    float4 v = *(const float4*)(src + i);
    ushort4 o;
    o.x = f2us(v.x); o.y = f2us(v.y); o.z = f2us(v.z); o.w = f2us(v.w);
    *(ushort4*)(dst + i) = o;
  }
}

// ---------------- MFMA bf16 NT GEMM: C[M,N] = A[M,K] @ B[N,K]^T ----------------
template<int OUT_BF16>
__global__ __launch_bounds__(256) void gemm_bt_mfma(
    const unsigned short* __restrict__ A, const unsigned short* __restrict__ B,
    void* __restrict__ Cout, int M, int N, int K) {
  __shared__ unsigned short sA[128*32];
  __shared__ unsigned short sB[128*32];
  const int tid  = threadIdx.x;
  const int lane = tid & 63;
  const int wave = tid >> 6;
  const int bm = blockIdx.y * 128;
  const int bn = blockIdx.x * 128;
  const int wm = (wave >> 1) * 64;
  const int wn = (wave & 1) * 64;
  const int fr = lane & 15;
  const int fq = lane >> 4;

  floatx4 acc[4][4];
  #pragma unroll
  for (int i = 0; i < 4; ++i)
    #pragma unroll
    for (int j = 0; j < 4; ++j) acc[i][j] = (floatx4){0.f, 0.f, 0.f, 0.f};

  const int g0 = tid * 8;
  for (int k0 = 0; k0 < K; k0 += 32) {
    __syncthreads();
    #pragma unroll
    for (int r = 0; r < 2; ++r) {
      int g = r * 2048 + g0;
      int row = g >> 5, col = g & 31;
      const unsigned short* gp = A + (size_t)(bm + row) * K + k0 + col;
      __builtin_amdgcn_global_load_lds(
          (const __attribute__((address_space(1))) uint32_t*)gp,
          (__attribute__((address_space(3))) uint32_t*)(sA + g), 16, 0, 0);
    }
    #pragma unroll
    for (int r = 0; r < 2; ++r) {
      int g = r * 2048 + g0;
      int row = g >> 5, col = g & 31;
      const unsigned short* gp = B + (size_t)(bn + row) * K + k0 + col;
      __builtin_amdgcn_global_load_lds(
          (const __attribute__((address_space(1))) uint32_t*)gp,
          (__attribute__((address_space(3))) uint32_t*)(sB + g), 16, 0, 0);
    }
    __syncthreads();

    short8 af[4], bfr[4];
    #pragma unroll
    for (int i = 0; i < 4; ++i)
      af[i] = *(const short8*)(sA + (wm + i*16 + fr) * 32 + fq * 8);
    #pragma unroll
    for (int j = 0; j < 4; ++j)
      bfr[j] = *(const short8*)(sB + (wn + j*16 + fr) * 32 + fq * 8);
    #pragma unroll
    for (int i = 0; i < 4; ++i)
      #pragma unroll
      for (int j = 0; j < 4; ++j)
        acc[i][j] = __builtin_amdgcn_mfma_f32_16x16x32_bf16(af[i], bfr[j], acc[i][j], 0, 0, 0);
  }

  #pragma unroll
  for (int i = 0; i < 4; ++i) {
    #pragma unroll
    for (int j = 0; j < 4; ++j) {
      int col = bn + wn + j*16 + fr;
      #pragma unroll
      for (int r = 0; r < 4; ++r) {
        int row = bm + wm + i*16 + fq*4 + r;
        if (OUT_BF16)
          ((unsigned short*)Cout)[(size_t)row * N + col] = f2us(acc[i][j][r]);
        else
          ((float*)Cout)[(size_t)row * N + col] = acc[i][j][r];
      }
    }
  }
}

// ---------------- fp32 tiled NT GEMM (fallback path only) ----------------
__device__ inline void loadA4(const float* p, float* d) {
  float4 v = *(const float4*)p; d[0]=v.x; d[1]=v.y; d[2]=v.z; d[3]=v.w;
}
__device__ inline void loadA4(const unsigned short* p, float* d) {
  ushort4 v = *(const ushort4*)p;
  d[0]=us2f(v.x); d[1]=us2f(v.y); d[2]=us2f(v.z); d[3]=us2f(v.w);
}
__device__ inline void store8(float* C, size_t off, const float* v) {
  *(float4*)(C + off)     = make_float4(v[0], v[1], v[2], v[3]);
  *(float4*)(C + off + 4) = make_float4(v[4], v[5], v[6], v[7]);
}
__device__ inline void store8(unsigned short* C, size_t off, const float* v) {
  ushort4 a; a.x=f2us(v[0]); a.y=f2us(v[1]); a.z=f2us(v[2]); a.w=f2us(v[3]);
  ushort4 b; b.x=f2us(v[4]); b.y=f2us(v[5]); b.z=f2us(v[6]); b.w=f2us(v[7]);
  *(ushort4*)(C + off) = a; *(ushort4*)(C + off + 4) = b;
}

template<typename AT, typename OT>
__global__ __launch_bounds__(256) void gemm_nt(
    const AT* __restrict__ A, const float* __restrict__ Bw,
    OT* __restrict__ C, int M, int N, int K) {
  __shared__ float As[16][128+4];
  __shared__ float Bs[16][128+4];
  const int bm = blockIdx.y * 128;
  const int bn = blockIdx.x * 128;
  const int tid = threadIdx.x;
  const int tx = tid & 15, ty = tid >> 4;

  float acc[8][8];
  #pragma unroll
  for (int i = 0; i < 8; ++i)
    #pragma unroll
    for (int j = 0; j < 8; ++j) acc[i][j] = 0.f;

  for (int k0 = 0; k0 < K; k0 += 16) {
    #pragma unroll
    for (int r = 0; r < 2; ++r) {
      int i = tid + r * 256;
      int m  = i >> 2;
      int kv = (i & 3) << 2;
      float va[4];
      loadA4(A + (size_t)(bm + m) * K + k0 + kv, va);
      As[kv+0][m] = va[0]; As[kv+1][m] = va[1]; As[kv+2][m] = va[2]; As[kv+3][m] = va[3];
      float vb[4] = {0.f, 0.f, 0.f, 0.f};
      if (bn + m < N) loadA4(Bw + (size_t)(bn + m) * K + k0 + kv, vb);
      Bs[kv+0][m] = vb[0]; Bs[kv+1][m] = vb[1]; Bs[kv+2][m] = vb[2]; Bs[kv+3][m] = vb[3];
    }
    __syncthreads();
    #pragma unroll
    for (int kk = 0; kk < 16; ++kk) {
      float ra[8], rb[8];
      *(float4*)&ra[0] = *(const float4*)&As[kk][ty*8];
      *(float4*)&ra[4] = *(const float4*)&As[kk][ty*8+4];
      *(float4*)&rb[0] = *(const float4*)&Bs[kk][tx*8];
      *(float4*)&rb[4] = *(const float4*)&Bs[kk][tx*8+4];
      #pragma unroll
      for (int i = 0; i < 8; ++i)
        #pragma unroll
        for (int j = 0; j < 8; ++j) acc[i][j] += ra[i] * rb[j];
    }
    __syncthreads();
  }
  #pragma unroll
  for (int i = 0; i < 8; ++i) {
    int m  = bm + ty*8 + i;
    int n0 = bn + tx*8;
    if (n0 < N) store8(C, (size_t)m * N + n0, &acc[i][0]);
  }
}

// ---------------- dt GEMV (fp32) ----------------
__global__ __launch_bounds__(256) void dt_gemv(
    const float* __restrict__ x, const float* __restrict__ W,
    float* __restrict__ dtr) {
  const int t = blockIdx.x;
  const int tid = threadIdx.x;
  __shared__ float xrow[DMODEL];
  for (int i = tid; i < DMODEL; i += 256) xrow[i] = x[(size_t)t * DMODEL + i];
  __syncthreads();
  const int h = tid >> 2, q = tid & 3;
  const float4* wp = (const float4*)(W + (size_t)(NPROJ + h) * DMODEL + q * 512);
  const float4* xp = (const float4*)(xrow + q * 512);
  float acc = 0.f;
  #pragma unroll 4
  for (int u = 0; u < 128; ++u) {
    float4 a = xp[u], b = wp[u];
    acc += a.x*b.x + a.y*b.y + a.z*b.z + a.w*b.w;
  }
  acc += __shfl_xor(acc, 1, 64);
  acc += __shfl_xor(acc, 2, 64);
  if (q == 0) dtr[(size_t)t * NHEADS + h] = acc;
}

// ================= split-scan path =================
__global__ __launch_bounds__(256) void bc_conv_g(
    const unsigned short* __restrict__ proj, const float* __restrict__ cw,
    const float* __restrict__ cb, unsigned short* __restrict__ bcact,
    float* __restrict__ gbuf) {
  const int c = blockIdx.x & 31;
  const int b = blockIdx.x >> 5;
  const int tid = threadIdx.x;
  const int t0 = b * SEQ + c * CHUNK;
  __shared__ unsigned short sB[64*130];
  __shared__ unsigned short sC[64*130];
  for (int i = tid; i < 64*256; i += 256) {
    int s = i >> 8, ch = i & 255;
    int cx = 4096 + ch;
    int lb = c * CHUNK + s;
    float acc = cb[cx];
    #pragma unroll
    for (int j = 0; j < 4; ++j) {
      int ll = lb - 3 + j;
      if (ll >= 0)
        acc += cw[cx*4 + j] * us2f(proj[(size_t)(b*SEQ + ll) * NPROJ + DINNER + cx]);
    }
    float v = acc / (1.f + expf(-acc));
    unsigned short uv = f2us(v);
    if (ch < 128) sB[s*130 + ch] = uv;
    else          sC[s*130 + (ch - 128)] = uv;
    bcact[(size_t)(t0 + s) * 256 + ch] = uv;
  }
  __syncthreads();
  const int l = tid >> 2, q = tid & 3;
  float g[16];
  #pragma unroll
  for (int j = 0; j < 16; ++j) g[j] = 0.f;
  const uint32_t* Cu = (const uint32_t*)&sC[l * 130];
  for (int u = 0; u < 64; ++u) {
    uint32_t cv = Cu[u];
    float c0 = plo(cv), c1 = phi(cv);
    #pragma unroll
    for (int j = 0; j < 16; ++j) {
      uint32_t bv = ((const uint32_t*)&sB[(q*16 + j) * 130])[u];
      g[j] += c0 * plo(bv) + c1 * phi(bv);
    }
  }
  float* gr = gbuf + ((size_t)(b*NCHUNK + c)) * 4096 + l*64 + q*16;
  #pragma unroll
  for (int j = 0; j < 16; ++j) gr[j] = g[j];
}

// ---- A2 (MFMA): per (b,c,h): dt/cumsum, conv X, Y_diag+D-skip, chunk state ----
// Y_diag = W' @ Xh^T (K=64), W'[l][s] = mask*G*exp(Ac[l]-Ac[s])*dt[s], Xh[p][s]=xh[s][p]
// cs     = Xh @ Bt'^T (K=64), Bt'[n][s] = B[s][n]*dt[s]*decay[s]
__global__ __launch_bounds__(256, 4) void ssd_phase_a2_mfma(
    const unsigned short* __restrict__ proj, const unsigned short* __restrict__ bcact,
    const float* __restrict__ dtr, const float* __restrict__ cw,
    const float* __restrict__ cb, const float* __restrict__ A_log,
    const float* __restrict__ dt_bias, const float* __restrict__ gbuf,
    const float* __restrict__ Dv,
    unsigned short* __restrict__ cs, float* __restrict__ acs,
    unsigned short* __restrict__ yscan) {
  const int h = blockIdx.x & 63;
  const int c = (blockIdx.x >> 6) & 31;
  const int b = blockIdx.x >> 11;
  const int tid = threadIdx.x;
  const int t0 = b * SEQ + c * CHUNK;
  const int lane = tid & 63, wave = tid >> 6;
  const int fr = lane & 15, fq = lane >> 4;

  __shared__ __align__(16) unsigned short sBt[128*72];  // Bt'[n][s]
  __shared__ __align__(16) unsigned short sXh[64*72];   // Xh[p][s] (transposed xh)
  __shared__ __align__(16) unsigned short sW[64*72];    // W'[l][s]
  __shared__ float sdt[64], sAc[64], sdecay[64];

  const float Ah = -expf(A_log[h]);
  if (tid < 64) {
    float raw = dtr[(size_t)(t0 + tid) * NHEADS + h] + dt_bias[h];
    float dt = (raw > 20.f) ? raw : log1pf(expf(raw));
    sdt[tid] = dt;
    float v = dt * Ah;
    #pragma unroll
    for (int off = 1; off < 64; off <<= 1) {
      float o = __shfl_up(v, off, 64);
      if (tid >= off) v += o;
    }
    sAc[tid] = v;
    float alast = __shfl(v, 63, 64);
    sdecay[tid] = expf(alast - v);
    acs[((size_t)((b*NHEADS + h)*NCHUNK + c))*64 + tid] = v;
  }
  __syncthreads();
  // Bt' staging (transposed write; 8-way b16 conflicts acceptable, see notes)
  for (int i = tid; i < 64*128; i += 256) {
    int s = i >> 7, n = i & 127;
    float v = us2f(bcact[(size_t)(t0 + s) * 256 + n]) * sdt[s] * sdecay[s];
    sBt[n*72 + s] = f2us(v);
  }
  // Xh staging: conv+silu on head channels, write transposed
  for (int i = tid; i < 64*64; i += 256) {
    int s = i >> 6, p = i & 63;
    int cx = h * HEADDIM + p;
    int lb = c * CHUNK + s;
    float acc = cb[cx];
    #pragma unroll
    for (int j = 0; j < 4; ++j) {
      int ll = lb - 3 + j;
      if (ll >= 0)
        acc += cw[cx*4 + j] * us2f(proj[(size_t)(b*SEQ + ll) * NPROJ + DINNER + cx]);
    }
    float xh = acc / (1.f + expf(-acc));
    sXh[p*72 + s] = f2us(xh);
  }
  // W' staging
  {
    const float* gr = gbuf + ((size_t)(b*NCHUNK + c)) * 4096;
    for (int i = tid; i < 4096; i += 256) {
      int l = i >> 6, s = i & 63;
      float w = (s <= l) ? gr[i] * expf(sAc[l] - sAc[s]) * sdt[s] : 0.f;
      sW[l*72 + s] = f2us(w);
    }
  }
  __syncthreads();

  // Y_diag: wave strip rows l in [16*wave, 16*wave+16), 4 p-tiles, K=64
  floatx4 accy[4];
  #pragma unroll
  for (int j = 0; j < 4; ++j) accy[j] = (floatx4){0.f, 0.f, 0.f, 0.f};
  #pragma unroll
  for (int k0 = 0; k0 < 64; k0 += 32) {
    short8 af = *(const short8*)(sW + (wave*16 + fr)*72 + k0 + fq*8);
    #pragma unroll
    for (int j = 0; j < 4; ++j) {
      short8 bf = *(const short8*)(sXh + (j*16 + fr)*72 + k0 + fq*8);
      accy[j] = __builtin_amdgcn_mfma_f32_16x16x32_bf16(af, bf, accy[j], 0, 0, 0);
    }
  }
  const float Dh = Dv[h];
  #pragma unroll
  for (int j = 0; j < 4; ++j) {
    int p = j*16 + fr;
    #pragma unroll
    for (int r = 0; r < 4; ++r) {
      int l = wave*16 + fq*4 + r;
      float yd = accy[j][r] + us2f(sXh[p*72 + l]) * Dh;
      yscan[(size_t)(t0 + l) * DINNER + h*HEADDIM + p] = f2us(yd);
    }
  }
  // chunk state: wave strip rows p in [16*wave, ...), 8 n-tiles, K=64
  floatx4 accs[8];
  #pragma unroll
  for (int j = 0; j < 8; ++j) accs[j] = (floatx4){0.f, 0.f, 0.f, 0.f};
  #pragma unroll
  for (int k0 = 0; k0 < 64; k0 += 32) {
    short8 af = *(const short8*)(sXh + (wave*16 + fr)*72 + k0 + fq*8);
    #pragma unroll
    for (int j = 0; j < 8; ++j) {
      short8 bf = *(const short8*)(sBt + (j*16 + fr)*72 + k0 + fq*8);
      accs[j] = __builtin_amdgcn_mfma_f32_16x16x32_bf16(af, bf, accs[j], 0, 0, 0);
    }
  }
  const size_t csb = ((size_t)((b*NHEADS + h)*NCHUNK + c)) * (HEADDIM*DSTATE);
  #pragma unroll
  for (int j = 0; j < 8; ++j) {
    int n = j*16 + fr;
    #pragma unroll
    for (int r = 0; r < 4; ++r) {
      int p = wave*16 + fq*4 + r;
      cs[csb + p*128 + n] = f2us(accs[j][r]);
    }
  }
}

// ---- B: inter-chunk running-state scan (reference quirk: post-chunk state) ----
__global__ __launch_bounds__(256) void ssd_scan_states(
    unsigned short* __restrict__ cs, const float* __restrict__ acs) {
  int idx = blockIdx.x * 256 + threadIdx.x;
  int e  = idx & 8191;
  int bh = idx >> 13;
  float S = 0.f;
  for (int c = 0; c < NCHUNK; ++c) {
    float al = acs[((size_t)bh*NCHUNK + c)*64 + 63];
    size_t o = ((size_t)bh*NCHUNK + c)*(HEADDIM*DSTATE) + e;
    S = S * expf(al) + us2f(cs[o]);
    cs[o] = f2us(S);
  }
}

// ---- C (MFMA): Y += (C @ S^T) * exp(Ac[l]) ; K=128, natural layouts ----
__global__ __launch_bounds__(256, 4) void ssd_phase_c_mfma(
    const unsigned short* __restrict__ bcact, const unsigned short* __restrict__ cs,
    const float* __restrict__ acs, unsigned short* __restrict__ yscan) {
  const int h = blockIdx.x & 63;
  const int c = (blockIdx.x >> 6) & 31;
  const int b = blockIdx.x >> 11;
  const int tid = threadIdx.x;
  const int t0 = b * SEQ + c * CHUNK;
  const int lane = tid & 63, wave = tid >> 6;
  const int fr = lane & 15, fq = lane >> 4;

  __shared__ __align__(16) unsigned short sC[64*136];  // C[l][n]
  __shared__ __align__(16) unsigned short sS[64*136];  // S[p][n]
  __shared__ float seAc[64];

  const size_t csb = ((size_t)((b*NHEADS + h)*NCHUNK + c)) * (HEADDIM*DSTATE);
  for (int i = tid; i < 8192; i += 256) {
    int p = i >> 7, n = i & 127;
    sS[p*136 + n] = cs[csb + i];
  }
  for (int i = tid; i < 8192; i += 256) {
    int l = i >> 7, n = i & 127;
    sC[l*136 + n] = bcact[(size_t)(t0 + l) * 256 + 128 + n];
  }
  if (tid < 64) seAc[tid] = expf(acs[((size_t)((b*NHEADS + h)*NCHUNK + c))*64 + tid]);
  __syncthreads();

  floatx4 acc[4];
  #pragma unroll
  for (int j = 0; j < 4; ++j) acc[j] = (floatx4){0.f, 0.f, 0.f, 0.f};
  #pragma unroll
  for (int k0 = 0; k0 < 128; k0 += 32) {
    short8 af = *(const short8*)(sC + (wave*16 + fr)*136 + k0 + fq*8);
    #pragma unroll
    for (int j = 0; j < 4; ++j) {
      short8 bf = *(const short8*)(sS + (j*16 + fr)*136 + k0 + fq*8);
      acc[j] = __builtin_amdgcn_mfma_f32_16x16x32_bf16(af, bf, acc[j], 0, 0, 0);
    }
  }
  #pragma unroll
  for (int j = 0; j < 4; ++j) {
    int p = j*16 + fr;
    #pragma unroll
    for (int r = 0; r < 4; ++r) {
      int l = wave*16 + fq*4 + r;
      size_t yi = (size_t)(t0 + l) * DINNER + h*HEADDIM + p;
      yscan[yi] = f2us(us2f(yscan[yi]) + acc[j][r] * seAc[l]);
    }
  }
}

__global__ __launch_bounds__(256) void gate_rmsnorm2(
    const unsigned short* __restrict__ proj, const float* __restrict__ norm_w,
    unsigned short* __restrict__ yscan) {
  const int t = blockIdx.x;
  const int tid = threadIdx.x;
  __shared__ float ybuf[DINNER];
  __shared__ float wpart[4];
  __shared__ float sinv;
  float ss = 0.f;
  for (int i = tid; i < DINNER; i += 256) {
    float zv = us2f(proj[(size_t)t * NPROJ + i]);
    float yv = us2f(yscan[(size_t)t * DINNER + i]) * (zv / (1.f + expf(-zv)));
    ybuf[i] = yv;
    ss += yv * yv;
  }
  #pragma unroll
  for (int off = 32; off > 0; off >>= 1) ss += __shfl_down(ss, off, 64);
  if ((tid & 63) == 0) wpart[tid >> 6] = ss;
  __syncthreads();
  if (tid == 0) {
    float tot = wpart[0] + wpart[1] + wpart[2] + wpart[3];
    sinv = 1.f / sqrtf(tot / (float)DINNER + 1e-5f);
  }
  __syncthreads();
  float inv = sinv;
  for (int i = tid; i < DINNER; i += 256)
    yscan[(size_t)t * DINNER + i] = f2us(ybuf[i] * inv * norm_w[i]);
}

// ================= FALLBACK path (round-1, proven; used if ws too small) ====
__global__ __launch_bounds__(512) void ssd_fused(
    const unsigned short* __restrict__ proj, const float* __restrict__ dtr,
    const float* __restrict__ cw, const float* __restrict__ cb,
    const float* __restrict__ A_log, const float* __restrict__ dt_bias,
    unsigned short* __restrict__ yscan) {
  const int h = blockIdx.x & 63;
  const int b = blockIdx.x >> 6;
  const int tid = threadIdx.x;

  __shared__ unsigned short sB[64*130];
  __shared__ unsigned short sC[64*130];
  __shared__ unsigned short sX[64*66];
  __shared__ float sW[64*65];
  __shared__ float sdt[64], sAc[64], sdecay[64], seAc[64];

  const float Ah = -expf(A_log[h]);
  const float dbias = dt_bias[h];

  float S[16];
  #pragma unroll
  for (int j = 0; j < 16; ++j) S[j] = 0.f;

  const int lG  = tid >> 3;
  const int oc  = tid & 7;

  for (int c = 0; c < NCHUNK; ++c) {
    const int t0 = b * SEQ + c * CHUNK;
    __syncthreads();
    if (tid < 64) {
      float raw = dtr[(size_t)(t0 + tid) * NHEADS + h] + dbias;
      sdt[tid] = (raw > 20.f) ? raw : log1pf(expf(raw));
    }
    for (int i = tid; i < 64*256; i += 512) {
      int s = i >> 8, ch = i & 255;
      int cx = 4096 + ch;
      int lb = c * CHUNK + s;
      float acc = cb[cx];
      #pragma unroll
      for (int j = 0; j < 4; ++j) {
        int ll = lb - 3 + j;
        if (ll >= 0)
          acc += cw[cx*4 + j] * us2f(proj[(size_t)(b*SEQ + ll) * NPROJ + DINNER + cx]);
      }
      float v = acc / (1.f + expf(-acc));
      if (ch < 128) sB[s*130 + ch] = f2us(v);
      else          sC[s*130 + (ch - 128)] = f2us(v);
    }
    __syncthreads();
    if (tid == 0) {
      float run = 0.f;
      for (int s = 0; s < CHUNK; ++s) { run += sdt[s] * Ah; sAc[s] = run; }
    }
    __syncthreads();
    if (tid < 64) {
      float last = sAc[63];
      sdecay[tid] = expf(last - sAc[tid]);
      seAc[tid]   = expf(sAc[tid]);
    }
    for (int i = tid; i < 64*64; i += 512) {
      int s = i >> 6, p = i & 63;
      int cx = h * HEADDIM + p;
      int lb = c * CHUNK + s;
      float acc = cb[cx];
      #pragma unroll
      for (int j = 0; j < 4; ++j) {
        int ll = lb - 3 + j;
        if (ll >= 0)
          acc += cw[cx*4 + j] * us2f(proj[(size_t)(b*SEQ + ll) * NPROJ + DINNER + cx]);
      }
      float v = acc / (1.f + expf(-acc));
      sX[s*66 + p] = f2us(v * sdt[s]);
    }
    __syncthreads();

    float g[8];
    #pragma unroll
    for (int j = 0; j < 8; ++j) g[j] = 0.f;
    {
      const uint32_t* Cu = (const uint32_t*)&sC[lG * 130];
      for (int u = 0; u < 64; ++u) {
        uint32_t cv = Cu[u];
        float c0 = plo(cv), c1 = phi(cv);
        #pragma unroll
        for (int j = 0; j < 8; ++j) {
          uint32_t bv = ((const uint32_t*)&sB[(oc*8 + j) * 130])[u];
          g[j] += c0 * plo(bv) + c1 * phi(bv);
        }
      }
    }
    {
      float acl = sAc[lG];
      #pragma unroll
      for (int j = 0; j < 8; ++j) {
        int s = oc*8 + j;
        sW[lG*65 + s] = (s <= lG) ? g[j] * expf(acl - sAc[s]) : 0.f;
      }
    }
    {
      float elast = expf(sAc[63]);
      #pragma unroll
      for (int j = 0; j < 16; ++j) S[j] *= elast;
      for (int s = 0; s < CHUNK; ++s) {
        float w = sdecay[s] * us2f(sX[s*66 + lG]);
        const uint32_t* Bu = (const uint32_t*)&sB[s*130 + oc*16];
        #pragma unroll
        for (int ju = 0; ju < 8; ++ju) {
          uint32_t bv = Bu[ju];
          S[2*ju]   += plo(bv) * w;
          S[2*ju+1] += phi(bv) * w;
        }
      }
    }
    __syncthreads();
    #pragma unroll
    for (int j = 0; j < 16; ++j) sB[lG*130 + oc*16 + j] = f2us(S[j]);
    __syncthreads();
    for (int o = tid; o < CHUNK*HEADDIM; o += 512) {
      int l = o >> 6, p = o & 63;
      float yd = 0.f;
      for (int s = 0; s <= l; ++s)
        yd += sW[l*65 + s] * us2f(sX[s*66 + p]);
      float yo = 0.f;
      const uint32_t* Cu = (const uint32_t*)&sC[l * 130];
      const uint32_t* Su = (const uint32_t*)&sB[p * 130];
      for (int u = 0; u < 64; ++u) {
        uint32_t cv = Cu[u], sv = Su[u];
        yo += plo(cv) * plo(sv) + phi(cv) * phi(sv);
      }
      float y = yd + yo * seAc[l];
      yscan[(size_t)(t0 + l) * DINNER + h * HEADDIM + p] = f2us(y);
    }
  }
}

__global__ __launch_bounds__(256) void gate_rmsnorm_dskip(
    const unsigned short* __restrict__ proj, const float* __restrict__ cw,
    const float* __restrict__ cb, const float* __restrict__ Dv,
    const float* __restrict__ norm_w, unsigned short* __restrict__ yscan) {
  const int t = blockIdx.x;
  const int tid = threadIdx.x;
  const int b = t >> 11, lb = t & 2047;
  __shared__ float ybuf[DINNER];
  __shared__ float wpart[4];
  __shared__ float sinv;
  float ss = 0.f;
  for (int i = tid; i < DINNER; i += 256) {
    float zv = us2f(proj[(size_t)t * NPROJ + i]);
    float acc = cb[i];
    #pragma unroll
    for (int j = 0; j < 4; ++j) {
      int ll = lb - 3 + j;
      if (ll >= 0)
        acc += cw[i*4 + j] * us2f(proj[(size_t)(b*SEQ + ll) * NPROJ + DINNER + i]);
    }
    float xh = acc / (1.f + expf(-acc));
    float yv = us2f(yscan[(size_t)t * DINNER + i]) + xh * Dv[i >> 6];
    yv = yv * (zv / (1.f + expf(-zv)));
    ybuf[i] = yv;
    ss += yv * yv;
  }
  #pragma unroll
  for (int off = 32; off > 0; off >>= 1) ss += __shfl_down(ss, off, 64);
  if ((tid & 63) == 0) wpart[tid >> 6] = ss;
  __syncthreads();
  if (tid == 0) {
    float tot = wpart[0] + wpart[1] + wpart[2] + wpart[3];
    sinv = 1.f / sqrtf(tot / (float)DINNER + 1e-5f);
  }
  __syncthreads();
  float inv = sinv;
  for (int i = tid; i < DINNER; i += 256)
    yscan[(size_t)t * DINNER + i] = f2us(ybuf[i] * inv * norm_w[i]);
}

// ---------------- launch ----------------
extern "C" void kernel_launch(void* const* d_in, const int* in_sizes, int n_in,
                              void* d_out, int out_size, void* d_ws, size_t ws_size,
                              hipStream_t stream) {
  const float* x          = (const float*)d_in[0];
  const float* in_proj_w  = (const float*)d_in[1];
  const float* conv_w     = (const float*)d_in[2];
  const float* conv_b     = (const float*)d_in[3];
  const float* A_log      = (const float*)d_in[4];
  const float* Dv         = (const float*)d_in[5];
  const float* dt_bias    = (const float*)d_in[6];
  const float* norm_w     = (const float*)d_in[7];
  const float* out_proj_w = (const float*)d_in[8];
  float* out = (float*)d_out;

  // ws carve-up (identical footprint to round 2/3)
  unsigned short* proj  = (unsigned short*)d_ws;
  float*          dtr   = (float*)(proj + (size_t)TOKENS * NPROJ);
  unsigned short* yscan = (unsigned short*)(dtr + (size_t)TOKENS * NHEADS);
  unsigned short* cs    = yscan + (size_t)TOKENS * DINNER;
  float*          acs   = (float*)(cs + (size_t)B_SZ*NHEADS*NCHUNK*HEADDIM*DSTATE);
  unsigned short* bcact = (unsigned short*)(acs + (size_t)B_SZ*NHEADS*NCHUNK*64);
  float*          gbuf  = (float*)(bcact + (size_t)TOKENS*256);
  const size_t NEEDED = (size_t)((char*)(gbuf + (size_t)B_SZ*NCHUNK*4096) - (char*)d_ws);

  unsigned short* xb  = cs;                                  // TOKENS*DMODEL
  unsigned short* wib = xb + (size_t)TOKENS * DMODEL;        // NPROJ*DMODEL
  unsigned short* wob = proj;                                // DMODEL*DINNER

  if (ws_size >= NEEDED) {
    cast_f32_bf16<<<(TOKENS*DMODEL)/1024, 256, 0, stream>>>(x, xb, TOKENS*DMODEL);
    cast_f32_bf16<<<((size_t)NPROJ*DMODEL)/1024, 256, 0, stream>>>(in_proj_w, wib, NPROJ*DMODEL);
    {
      dim3 grid(NPROJ/128, TOKENS/128);
      gemm_bt_mfma<1><<<grid, 256, 0, stream>>>(xb, wib, proj, TOKENS, NPROJ, DMODEL);
    }
    dt_gemv<<<TOKENS, 256, 0, stream>>>(x, in_proj_w, dtr);
    bc_conv_g<<<B_SZ*NCHUNK, 256, 0, stream>>>(proj, conv_w, conv_b, bcact, gbuf);
    ssd_phase_a2_mfma<<<B_SZ*NCHUNK*NHEADS, 256, 0, stream>>>(
        proj, bcact, dtr, conv_w, conv_b, A_log, dt_bias, gbuf, Dv, cs, acs, yscan);
    ssd_scan_states<<<(B_SZ*NHEADS*HEADDIM*DSTATE)/256, 256, 0, stream>>>(cs, acs);
    ssd_phase_c_mfma<<<B_SZ*NCHUNK*NHEADS, 256, 0, stream>>>(bcact, cs, acs, yscan);
    gate_rmsnorm2<<<TOKENS, 256, 0, stream>>>(proj, norm_w, yscan);
    cast_f32_bf16<<<((size_t)DMODEL*DINNER)/1024, 256, 0, stream>>>(out_proj_w, wob, DMODEL*DINNER);
    {
      dim3 grid(DMODEL/128, TOKENS/128);
      gemm_bt_mfma<0><<<grid, 256, 0, stream>>>(yscan, wob, out, TOKENS, DMODEL, DINNER);
    }
  } else {
    {
      dim3 grid(NPROJ/128, TOKENS/128);
      gemm_nt<float, unsigned short><<<grid, 256, 0, stream>>>(
          x, in_proj_w, proj, TOKENS, NPROJ, DMODEL);
    }
    dt_gemv<<<TOKENS, 256, 0, stream>>>(x, in_proj_w, dtr);
    ssd_fused<<<B_SZ*NHEADS, 512, 0, stream>>>(proj, dtr, conv_w, conv_b,
                                               A_log, dt_bias, yscan);
    gate_rmsnorm_dskip<<<TOKENS, 256, 0, stream>>>(proj, conv_w, conv_b, Dv, norm_w, yscan);
    {
      dim3 grid(DMODEL/128, TOKENS/128);
      gemm_nt<unsigned short, float><<<grid, 256, 0, stream>>>(
          yscan, out_proj_w, out, TOKENS, DMODEL, DINNER);
    }
  }
}